// Round 1
// baseline (899.475 us; speedup 1.0000x reference)
//
#include <hip/hip_runtime.h>
#include <hip/hip_bf16.h>

#define NNODES 100000
#define NEDGES 800000
#define HIDDIM 128
#define NHEAD 4

// ---------------- CSR build ----------------

__global__ void init_deg_k(int* __restrict__ deg) {
    int i = blockIdx.x * blockDim.x + threadIdx.x;
    if (i < NNODES) deg[i] = 1;  // self-loop
}

__global__ void hist_k(const int* __restrict__ dst, int* __restrict__ deg) {
    int e = blockIdx.x * blockDim.x + threadIdx.x;
    if (e < NEDGES) atomicAdd(&deg[dst[e]], 1);
}

__global__ void scan1_k(const int* __restrict__ deg, int* __restrict__ offs,
                        int* __restrict__ blkSums) {
    __shared__ int sd[1024];
    int t = threadIdx.x;
    int i = blockIdx.x * 1024 + t;
    int v = (i < NNODES) ? deg[i] : 0;
    sd[t] = v;
    __syncthreads();
    for (int off = 1; off < 1024; off <<= 1) {
        int tv = (t >= off) ? sd[t - off] : 0;
        __syncthreads();
        sd[t] += tv;
        __syncthreads();
    }
    if (i < NNODES) offs[i] = sd[t] - v;  // exclusive within block
    if (t == 1023) blkSums[blockIdx.x] = sd[1023];
}

__global__ void scan2_k(int* __restrict__ blkSums, int nb) {
    __shared__ int sd[128];
    int t = threadIdx.x;
    int v = (t < nb) ? blkSums[t] : 0;
    sd[t] = v;
    __syncthreads();
    for (int off = 1; off < 128; off <<= 1) {
        int tv = (t >= off) ? sd[t - off] : 0;
        __syncthreads();
        sd[t] += tv;
        __syncthreads();
    }
    if (t < nb) blkSums[t] = sd[t] - v;  // exclusive block offsets
}

__global__ void scan3_k(int* __restrict__ offs, const int* __restrict__ blkSums,
                        int* __restrict__ cursor) {
    int i = blockIdx.x * 1024 + threadIdx.x;
    if (i < NNODES) {
        int v = offs[i] + blkSums[blockIdx.x];
        offs[i] = v;
        cursor[i] = v;
    }
}

__global__ void scatter_k(const int* __restrict__ srcRow, const int* __restrict__ dstRow,
                          int* __restrict__ cursor, int* __restrict__ srcs) {
    int t = blockIdx.x * blockDim.x + threadIdx.x;
    if (t < NEDGES) {
        int d = dstRow[t];
        int pos = atomicAdd(&cursor[d], 1);
        srcs[pos] = srcRow[t];
    } else if (t < NEDGES + NNODES) {
        int n = t - NEDGES;
        int pos = atomicAdd(&cursor[n], 1);
        srcs[pos] = n;  // self-loop
    }
}

// ---------------- GEMM: C[M,128] = A[M,128] @ B[128,128], fp32 ----------------

__global__ __launch_bounds__(256) void gemm_k(const float* __restrict__ A,
                                              const float* __restrict__ B,
                                              float* __restrict__ C, int M) {
    __shared__ float As[32][33];
    __shared__ float Bs[32][HIDDIM];
    const int tid = threadIdx.x;
    const int tx = tid & 31;   // col group -> cols tx*4 .. tx*4+3
    const int ty = tid >> 5;   // row group -> rows ty*4 .. ty*4+3
    const int brow = blockIdx.x * 32;

    float4 acc0 = make_float4(0.f, 0.f, 0.f, 0.f);
    float4 acc1 = acc0, acc2 = acc0, acc3 = acc0;

    for (int kt = 0; kt < 128; kt += 32) {
        {
            int r = tid >> 3, c4 = (tid & 7) * 4;
            int grow = brow + r;
            float4 av = (grow < M) ? *(const float4*)(A + (size_t)grow * 128 + kt + c4)
                                   : make_float4(0.f, 0.f, 0.f, 0.f);
            As[r][c4 + 0] = av.x; As[r][c4 + 1] = av.y;
            As[r][c4 + 2] = av.z; As[r][c4 + 3] = av.w;
        }
        {
            int c4 = (tid & 31) * 4;
            int r0 = tid >> 5;
            #pragma unroll
            for (int rr = 0; rr < 4; rr++) {
                int r = r0 + rr * 8;
                *(float4*)(&Bs[r][c4]) = *(const float4*)(B + (size_t)(kt + r) * HIDDIM + c4);
            }
        }
        __syncthreads();
        #pragma unroll
        for (int k = 0; k < 32; k++) {
            float a0 = As[ty * 4 + 0][k];
            float a1 = As[ty * 4 + 1][k];
            float a2 = As[ty * 4 + 2][k];
            float a3 = As[ty * 4 + 3][k];
            float4 bv = *(float4*)(&Bs[k][tx * 4]);
            acc0.x += a0 * bv.x; acc0.y += a0 * bv.y; acc0.z += a0 * bv.z; acc0.w += a0 * bv.w;
            acc1.x += a1 * bv.x; acc1.y += a1 * bv.y; acc1.z += a1 * bv.z; acc1.w += a1 * bv.w;
            acc2.x += a2 * bv.x; acc2.y += a2 * bv.y; acc2.z += a2 * bv.z; acc2.w += a2 * bv.w;
            acc3.x += a3 * bv.x; acc3.y += a3 * bv.y; acc3.z += a3 * bv.z; acc3.w += a3 * bv.w;
        }
        __syncthreads();
    }
    {
        int row = brow + ty * 4;
        if (row + 3 < M) {
            *(float4*)(C + (size_t)(row + 0) * HIDDIM + tx * 4) = acc0;
            *(float4*)(C + (size_t)(row + 1) * HIDDIM + tx * 4) = acc1;
            *(float4*)(C + (size_t)(row + 2) * HIDDIM + tx * 4) = acc2;
            *(float4*)(C + (size_t)(row + 3) * HIDDIM + tx * 4) = acc3;
        } else {
            float4 a[4] = {acc0, acc1, acc2, acc3};
            for (int i = 0; i < 4; i++)
                if (row + i < M) *(float4*)(C + (size_t)(row + i) * HIDDIM + tx * 4) = a[i];
        }
    }
}

// ---------------- attention logits: aS/aD[n,h] = sum_c h[n,h,c]*att[h,c] ----------------

__global__ __launch_bounds__(256) void attn_k(const float* __restrict__ h,
                                              const float* __restrict__ att_src,
                                              const float* __restrict__ att_dst,
                                              float* __restrict__ aS, float* __restrict__ aD) {
    int lane = threadIdx.x & 63;
    int n = blockIdx.x * 4 + (threadIdx.x >> 6);
    if (n >= NNODES) return;
    int c2 = lane * 2;
    float2 hv = *(const float2*)(h + (size_t)n * HIDDIM + c2);
    float ps = hv.x * att_src[c2] + hv.y * att_src[c2 + 1];
    float pd = hv.x * att_dst[c2] + hv.y * att_dst[c2 + 1];
    #pragma unroll
    for (int m = 1; m < 16; m <<= 1) {
        ps += __shfl_xor(ps, m);
        pd += __shfl_xor(pd, m);
    }
    if ((lane & 15) == 0) {
        aS[n * NHEAD + (lane >> 4)] = ps;
        aD[n * NHEAD + (lane >> 4)] = pd;
    }
}

// ---------------- aggregate: one wave per dst node ----------------

__global__ __launch_bounds__(256) void agg_k(const float* __restrict__ h,
                                             const int* __restrict__ offs,
                                             const int* __restrict__ deg,
                                             const int* __restrict__ srcs,
                                             const float* __restrict__ aS,
                                             const float* __restrict__ aD,
                                             const float* __restrict__ bias,
                                             float* __restrict__ out) {
    int lane = threadIdx.x & 63;
    int n = blockIdx.x * 4 + (threadIdx.x >> 6);
    if (n >= NNODES) return;
    int head = lane >> 4;
    int c2 = lane * 2;
    int start = offs[n];
    int cnt = deg[n];
    float ad = aD[n * NHEAD + head];
    float ax = 0.f, ay = 0.f, wsum = 0.f;
    for (int base = 0; base < cnt; base += 64) {
        int m = min(64, cnt - base);
        int sv = (lane < m) ? srcs[start + base + lane] : 0;
        for (int j = 0; j < m; j++) {
            int s = __shfl(sv, j);
            float e = aS[s * NHEAD + head] + ad;
            e = (e > 0.f) ? e : 0.2f * e;
            float w = __expf(e);
            float2 hv = *(const float2*)(h + (size_t)s * HIDDIM + c2);
            ax += w * hv.x;
            ay += w * hv.y;
            wsum += w;
        }
    }
    float inv = 1.f / (wsum + 1e-16f);
    float o0 = ax * inv + bias[c2];
    float o1 = ay * inv + bias[c2 + 1];
    o0 = (o0 > 0.f) ? o0 : 0.f;
    o1 = (o1 > 0.f) ? o1 : 0.f;
    out[(size_t)n * HIDDIM + c2] = o0;
    out[(size_t)n * HIDDIM + c2 + 1] = o1;
}

// ---------------- launch ----------------

extern "C" void kernel_launch(void* const* d_in, const int* in_sizes, int n_in,
                              void* d_out, int out_size, void* d_ws, size_t ws_size,
                              hipStream_t stream) {
    (void)in_sizes; (void)n_in; (void)out_size; (void)ws_size;
    const float* x = (const float*)d_in[0];

    char* ws = (char*)d_ws;
    size_t off = 0;
    auto alloc = [&](size_t bytes) -> void* {
        void* p = ws + off;
        off += (bytes + 255) & ~(size_t)255;
        return p;
    };
    float* bufA = (float*)alloc((size_t)NNODES * HIDDIM * 4);
    float* bufB = (float*)alloc((size_t)NNODES * HIDDIM * 4);
    float* bufH = (float*)alloc((size_t)NNODES * HIDDIM * 4);
    float* aS   = (float*)alloc((size_t)NNODES * NHEAD * 4);
    float* aD   = (float*)alloc((size_t)NNODES * NHEAD * 4);
    int* deg     = (int*)alloc((size_t)NNODES * 4);
    int* offsArr = (int*)alloc((size_t)NNODES * 4);
    int* cursor  = (int*)alloc((size_t)NNODES * 4);
    int* srcs    = (int*)alloc((size_t)(NEDGES + NNODES) * 4);
    int* blkSums = (int*)alloc(128 * 4);

    const int nScan = (NNODES + 1023) / 1024;  // 98
    const float* in_ptr = x;
    for (int l = 0; l < 3; l++) {
        const int* ei      = (const int*)d_in[1 + 5 * l];
        const float* Wm    = (const float*)d_in[2 + 5 * l];
        const float* attS  = (const float*)d_in[3 + 5 * l];
        const float* attD  = (const float*)d_in[4 + 5 * l];
        const float* biasv = (const float*)d_in[5 + 5 * l];
        const int* srcRow = ei;
        const int* dstRow = ei + NEDGES;
        float* outp = (l == 0) ? bufA : (l == 1) ? bufB : (float*)d_out;

        hipLaunchKernelGGL(init_deg_k, dim3((NNODES + 255) / 256), dim3(256), 0, stream, deg);
        hipLaunchKernelGGL(hist_k, dim3((NEDGES + 255) / 256), dim3(256), 0, stream, dstRow, deg);
        hipLaunchKernelGGL(scan1_k, dim3(nScan), dim3(1024), 0, stream, deg, offsArr, blkSums);
        hipLaunchKernelGGL(scan2_k, dim3(1), dim3(128), 0, stream, blkSums, nScan);
        hipLaunchKernelGGL(scan3_k, dim3(nScan), dim3(1024), 0, stream, offsArr, blkSums, cursor);
        hipLaunchKernelGGL(scatter_k, dim3((NEDGES + NNODES + 255) / 256), dim3(256), 0, stream,
                           srcRow, dstRow, cursor, srcs);
        hipLaunchKernelGGL(gemm_k, dim3((NNODES + 31) / 32), dim3(256), 0, stream,
                           in_ptr, Wm, bufH, NNODES);
        hipLaunchKernelGGL(attn_k, dim3((NNODES + 3) / 4), dim3(256), 0, stream,
                           bufH, attS, attD, aS, aD);
        hipLaunchKernelGGL(agg_k, dim3((NNODES + 3) / 4), dim3(256), 0, stream,
                           bufH, offsArr, deg, srcs, aS, aD, biasv, outp);
        in_ptr = outp;
    }
}

// Round 2
// 869.608 us; speedup vs baseline: 1.0343x; 1.0343x over previous
//
#include <hip/hip_runtime.h>
#include <hip/hip_bf16.h>
#include <hip/hip_fp16.h>

#define NNODES 100000
#define NEDGES 800000
#define HIDDIM 128
#define NHEAD 4

// ---------------- CSR build ----------------

__global__ void init_deg_k(int* __restrict__ deg) {
    int i = blockIdx.x * blockDim.x + threadIdx.x;
    if (i < NNODES) deg[i] = 1;  // self-loop
}

__global__ void hist_k(const int* __restrict__ dst, int* __restrict__ deg) {
    int e = blockIdx.x * blockDim.x + threadIdx.x;
    if (e < NEDGES) atomicAdd(&deg[dst[e]], 1);
}

__global__ void scan1_k(const int* __restrict__ deg, int* __restrict__ offs,
                        int* __restrict__ blkSums) {
    __shared__ int sd[1024];
    int t = threadIdx.x;
    int i = blockIdx.x * 1024 + t;
    int v = (i < NNODES) ? deg[i] : 0;
    sd[t] = v;
    __syncthreads();
    for (int off = 1; off < 1024; off <<= 1) {
        int tv = (t >= off) ? sd[t - off] : 0;
        __syncthreads();
        sd[t] += tv;
        __syncthreads();
    }
    if (i < NNODES) offs[i] = sd[t] - v;  // exclusive within block
    if (t == 1023) blkSums[blockIdx.x] = sd[1023];
}

__global__ void scan2_k(int* __restrict__ blkSums, int nb) {
    __shared__ int sd[128];
    int t = threadIdx.x;
    int v = (t < nb) ? blkSums[t] : 0;
    sd[t] = v;
    __syncthreads();
    for (int off = 1; off < 128; off <<= 1) {
        int tv = (t >= off) ? sd[t - off] : 0;
        __syncthreads();
        sd[t] += tv;
        __syncthreads();
    }
    if (t < nb) blkSums[t] = sd[t] - v;  // exclusive block offsets
}

__global__ void scan3_k(int* __restrict__ offs, const int* __restrict__ blkSums,
                        int* __restrict__ cursor) {
    int i = blockIdx.x * 1024 + threadIdx.x;
    if (i < NNODES) {
        int v = offs[i] + blkSums[blockIdx.x];
        offs[i] = v;
        cursor[i] = v;
    }
}

__global__ void scatter_k(const int* __restrict__ srcRow, const int* __restrict__ dstRow,
                          int* __restrict__ cursor, int* __restrict__ srcs) {
    int t = blockIdx.x * blockDim.x + threadIdx.x;
    if (t < NEDGES) {
        int d = dstRow[t];
        int pos = atomicAdd(&cursor[d], 1);
        srcs[pos] = srcRow[t];
    } else if (t < NEDGES + NNODES) {
        int n = t - NEDGES;
        int pos = atomicAdd(&cursor[n], 1);
        srcs[pos] = n;  // self-loop
    }
}

// ---------------- GEMM: C[M,128] = A[M,128] @ B[128,128], fp32 ----------------
// 128x128 tile, BK=32, 256 threads, 8x8 accum per thread.
// A staged TRANSPOSED in LDS (Ast[k][m], pad to 132 so rows stay 16B-aligned)
// so inner loop is ds_read_b128 only.

__global__ __launch_bounds__(256) void gemm_k(const float* __restrict__ A,
                                              const float* __restrict__ B,
                                              float* __restrict__ C,
                                              __half* __restrict__ C16, int M) {
    __shared__ float Ast[32][132];
    __shared__ float Bs[32][HIDDIM];
    const int tid = threadIdx.x;
    const int tx = tid & 15;        // col group: cols tx*8 .. tx*8+7
    const int ty = tid >> 4;        // row group: rows ty*8 .. ty*8+7
    const int c8 = tx * 8;
    const int r0 = ty * 8;
    const int brow = blockIdx.x * 128;

    float4 acc[8][2];
    #pragma unroll
    for (int i = 0; i < 8; i++) {
        acc[i][0] = make_float4(0.f, 0.f, 0.f, 0.f);
        acc[i][1] = make_float4(0.f, 0.f, 0.f, 0.f);
    }

    const int lar = tid >> 3;        // 0..31  (row within 32-row slab)
    const int lac = (tid & 7) * 4;   // 0..28  (k offset)

    for (int kt = 0; kt < 128; kt += 32) {
        // stage A (transposed): 128 rows x 32 k
        #pragma unroll
        for (int p = 0; p < 4; p++) {
            int row = brow + lar + p * 32;
            float4 v = (row < M) ? *(const float4*)(A + (size_t)row * HIDDIM + kt + lac)
                                 : make_float4(0.f, 0.f, 0.f, 0.f);
            Ast[lac + 0][lar + p * 32] = v.x;
            Ast[lac + 1][lar + p * 32] = v.y;
            Ast[lac + 2][lar + p * 32] = v.z;
            Ast[lac + 3][lar + p * 32] = v.w;
        }
        // stage B: 32 x 128
        {
            int c4 = (tid & 31) * 4;
            int rb0 = tid >> 5;
            #pragma unroll
            for (int i = 0; i < 4; i++) {
                int rb = rb0 + i * 8;
                *(float4*)(&Bs[rb][c4]) = *(const float4*)(B + (size_t)(kt + rb) * HIDDIM + c4);
            }
        }
        __syncthreads();
        #pragma unroll 8
        for (int k = 0; k < 32; k++) {
            float4 a0 = *(float4*)(&Ast[k][r0]);
            float4 a1 = *(float4*)(&Ast[k][r0 + 4]);
            float4 b0 = *(float4*)(&Bs[k][c8]);
            float4 b1 = *(float4*)(&Bs[k][c8 + 4]);
            float ar[8] = {a0.x, a0.y, a0.z, a0.w, a1.x, a1.y, a1.z, a1.w};
            #pragma unroll
            for (int i = 0; i < 8; i++) {
                acc[i][0].x += ar[i] * b0.x; acc[i][0].y += ar[i] * b0.y;
                acc[i][0].z += ar[i] * b0.z; acc[i][0].w += ar[i] * b0.w;
                acc[i][1].x += ar[i] * b1.x; acc[i][1].y += ar[i] * b1.y;
                acc[i][1].z += ar[i] * b1.z; acc[i][1].w += ar[i] * b1.w;
            }
        }
        __syncthreads();
    }
    #pragma unroll
    for (int i = 0; i < 8; i++) {
        int row = brow + r0 + i;
        if (row < M) {
            *(float4*)(C + (size_t)row * HIDDIM + c8) = acc[i][0];
            *(float4*)(C + (size_t)row * HIDDIM + c8 + 4) = acc[i][1];
            union { __half2 h2[4]; uint4 u; } pk;
            pk.h2[0] = __floats2half2_rn(acc[i][0].x, acc[i][0].y);
            pk.h2[1] = __floats2half2_rn(acc[i][0].z, acc[i][0].w);
            pk.h2[2] = __floats2half2_rn(acc[i][1].x, acc[i][1].y);
            pk.h2[3] = __floats2half2_rn(acc[i][1].z, acc[i][1].w);
            *(uint4*)(C16 + (size_t)row * HIDDIM + c8) = pk.u;
        }
    }
}

// ---------------- attention logits ----------------

__global__ __launch_bounds__(256) void attn_k(const float* __restrict__ h,
                                              const float* __restrict__ att_src,
                                              const float* __restrict__ att_dst,
                                              float* __restrict__ aS, float* __restrict__ aD) {
    int lane = threadIdx.x & 63;
    int n = blockIdx.x * 4 + (threadIdx.x >> 6);
    if (n >= NNODES) return;
    int c2 = lane * 2;
    float2 hv = *(const float2*)(h + (size_t)n * HIDDIM + c2);
    float ps = hv.x * att_src[c2] + hv.y * att_src[c2 + 1];
    float pd = hv.x * att_dst[c2] + hv.y * att_dst[c2 + 1];
    #pragma unroll
    for (int m = 1; m < 16; m <<= 1) {
        ps += __shfl_xor(ps, m);
        pd += __shfl_xor(pd, m);
    }
    if ((lane & 15) == 0) {
        aS[n * NHEAD + (lane >> 4)] = ps;
        aD[n * NHEAD + (lane >> 4)] = pd;
    }
}

// ---------------- aggregate: one wave per dst node, fp16 h gather ----------------

__global__ __launch_bounds__(256) void agg_k(const __half* __restrict__ h16,
                                             const int* __restrict__ offs,
                                             const int* __restrict__ deg,
                                             const int* __restrict__ srcs,
                                             const float* __restrict__ aS,
                                             const float* __restrict__ aD,
                                             const float* __restrict__ bias,
                                             float* __restrict__ out) {
    int lane = threadIdx.x & 63;
    int n = blockIdx.x * 4 + (threadIdx.x >> 6);
    if (n >= NNODES) return;
    int head = lane >> 4;
    int c2 = lane * 2;
    int start = offs[n];
    int cnt = deg[n];
    float ad = aD[n * NHEAD + head];
    float ax = 0.f, ay = 0.f, wsum = 0.f;
    for (int base = 0; base < cnt; base += 64) {
        int m = min(64, cnt - base);
        int sv = (lane < m) ? srcs[start + base + lane] : 0;
        for (int j = 0; j < m; j++) {
            int s = __shfl(sv, j);
            float e = aS[s * NHEAD + head] + ad;
            e = (e > 0.f) ? e : 0.2f * e;
            float w = __expf(e);
            float2 hv = __half22float2(*(const __half2*)(h16 + (size_t)s * HIDDIM + c2));
            ax += w * hv.x;
            ay += w * hv.y;
            wsum += w;
        }
    }
    float inv = 1.f / (wsum + 1e-16f);
    float o0 = ax * inv + bias[c2];
    float o1 = ay * inv + bias[c2 + 1];
    o0 = (o0 > 0.f) ? o0 : 0.f;
    o1 = (o1 > 0.f) ? o1 : 0.f;
    out[(size_t)n * HIDDIM + c2] = o0;
    out[(size_t)n * HIDDIM + c2 + 1] = o1;
}

// ---------------- launch ----------------

extern "C" void kernel_launch(void* const* d_in, const int* in_sizes, int n_in,
                              void* d_out, int out_size, void* d_ws, size_t ws_size,
                              hipStream_t stream) {
    (void)in_sizes; (void)n_in; (void)out_size; (void)ws_size;
    const float* x = (const float*)d_in[0];

    char* ws = (char*)d_ws;
    size_t off = 0;
    auto alloc = [&](size_t bytes) -> void* {
        void* p = ws + off;
        off += (bytes + 255) & ~(size_t)255;
        return p;
    };
    float* bufA   = (float*)alloc((size_t)NNODES * HIDDIM * 4);   // layer outputs
    float* bufH   = (float*)alloc((size_t)NNODES * HIDDIM * 4);   // fp32 h (for attn)
    __half* h16   = (__half*)alloc((size_t)NNODES * HIDDIM * 2);  // fp16 h (for gather)
    float* aS     = (float*)alloc((size_t)NNODES * NHEAD * 4);
    float* aD     = (float*)alloc((size_t)NNODES * NHEAD * 4);
    int* deg      = (int*)alloc((size_t)NNODES * 4);
    int* offsArr  = (int*)alloc((size_t)NNODES * 4);
    int* cursor   = (int*)alloc((size_t)NNODES * 4);
    int* srcs     = (int*)alloc((size_t)(NEDGES + NNODES) * 4);
    int* blkSums  = (int*)alloc(128 * 4);

    const int nScan = (NNODES + 1023) / 1024;  // 98
    const float* in_ptr = x;
    for (int l = 0; l < 3; l++) {
        const int* ei      = (const int*)d_in[1 + 5 * l];
        const float* Wm    = (const float*)d_in[2 + 5 * l];
        const float* attS  = (const float*)d_in[3 + 5 * l];
        const float* attD  = (const float*)d_in[4 + 5 * l];
        const float* biasv = (const float*)d_in[5 + 5 * l];
        const int* srcRow = ei;
        const int* dstRow = ei + NEDGES;
        // l0 out -> bufA; l1 out -> bufA (its input is already consumed by gemm);
        // l2 out -> d_out. Stream order makes the in-place swap safe.
        float* outp = (l == 2) ? (float*)d_out : bufA;

        hipLaunchKernelGGL(init_deg_k, dim3((NNODES + 255) / 256), dim3(256), 0, stream, deg);
        hipLaunchKernelGGL(hist_k, dim3((NEDGES + 255) / 256), dim3(256), 0, stream, dstRow, deg);
        hipLaunchKernelGGL(scan1_k, dim3(nScan), dim3(1024), 0, stream, deg, offsArr, blkSums);
        hipLaunchKernelGGL(scan2_k, dim3(1), dim3(128), 0, stream, blkSums, nScan);
        hipLaunchKernelGGL(scan3_k, dim3(nScan), dim3(1024), 0, stream, offsArr, blkSums, cursor);
        hipLaunchKernelGGL(scatter_k, dim3((NEDGES + NNODES + 255) / 256), dim3(256), 0, stream,
                           srcRow, dstRow, cursor, srcs);
        hipLaunchKernelGGL(gemm_k, dim3((NNODES + 127) / 128), dim3(256), 0, stream,
                           in_ptr, Wm, bufH, h16, NNODES);
        hipLaunchKernelGGL(attn_k, dim3((NNODES + 3) / 4), dim3(256), 0, stream,
                           bufH, attS, attD, aS, aD);
        hipLaunchKernelGGL(agg_k, dim3((NNODES + 3) / 4), dim3(256), 0, stream,
                           h16, offsArr, deg, srcs, aS, aD, biasv, outp);
        in_ptr = outp;
    }
}

// Round 3
// 754.732 us; speedup vs baseline: 1.1918x; 1.1522x over previous
//
#include <hip/hip_runtime.h>
#include <hip/hip_bf16.h>
#include <hip/hip_fp16.h>

#define NNODES 100000
#define NEDGES 800000
#define HIDDIM 128
#define NHEAD 4

// ---------------- CSR build ----------------

__global__ void init_deg_k(int* __restrict__ deg) {
    int i = blockIdx.x * blockDim.x + threadIdx.x;
    if (i < NNODES) deg[i] = 1;  // self-loop
}

__global__ void hist_k(const int* __restrict__ dst, int* __restrict__ deg) {
    int e = blockIdx.x * blockDim.x + threadIdx.x;
    if (e < NEDGES) atomicAdd(&deg[dst[e]], 1);
}

__global__ void scan1_k(const int* __restrict__ deg, int* __restrict__ offs,
                        int* __restrict__ blkSums) {
    __shared__ int sd[1024];
    int t = threadIdx.x;
    int i = blockIdx.x * 1024 + t;
    int v = (i < NNODES) ? deg[i] : 0;
    sd[t] = v;
    __syncthreads();
    for (int off = 1; off < 1024; off <<= 1) {
        int tv = (t >= off) ? sd[t - off] : 0;
        __syncthreads();
        sd[t] += tv;
        __syncthreads();
    }
    if (i < NNODES) offs[i] = sd[t] - v;  // exclusive within block
    if (t == 1023) blkSums[blockIdx.x] = sd[1023];
}

__global__ void scan2_k(int* __restrict__ blkSums, int nb) {
    __shared__ int sd[128];
    int t = threadIdx.x;
    int v = (t < nb) ? blkSums[t] : 0;
    sd[t] = v;
    __syncthreads();
    for (int off = 1; off < 128; off <<= 1) {
        int tv = (t >= off) ? sd[t - off] : 0;
        __syncthreads();
        sd[t] += tv;
        __syncthreads();
    }
    if (t < nb) blkSums[t] = sd[t] - v;  // exclusive block offsets
}

__global__ void scan3_k(int* __restrict__ offs, const int* __restrict__ blkSums,
                        int* __restrict__ cursor) {
    int i = blockIdx.x * 1024 + threadIdx.x;
    if (i < NNODES) {
        int v = offs[i] + blkSums[blockIdx.x];
        offs[i] = v;
        cursor[i] = v;
    }
}

__global__ void scatter_k(const int* __restrict__ srcRow, const int* __restrict__ dstRow,
                          int* __restrict__ cursor, int* __restrict__ srcs) {
    int t = blockIdx.x * blockDim.x + threadIdx.x;
    if (t < NEDGES) {
        int d = dstRow[t];
        int pos = atomicAdd(&cursor[d], 1);
        srcs[pos] = srcRow[t];
    } else if (t < NEDGES + NNODES) {
        int n = t - NEDGES;
        int pos = atomicAdd(&cursor[n], 1);
        srcs[pos] = n;  // self-loop
    }
}

// ---------------- GEMM: h16[M,128] = fp16(A[M,128] @ B[128,128]) ----------------
// 128x128 tile, BK=32, 256 threads, 8x8 accum per thread.
// A staged TRANSPOSED in LDS so inner loop is ds_read_b128 only.

__global__ __launch_bounds__(256) void gemm_k(const float* __restrict__ A,
                                              const float* __restrict__ B,
                                              __half* __restrict__ C16, int M) {
    __shared__ float Ast[32][132];
    __shared__ float Bs[32][HIDDIM];
    const int tid = threadIdx.x;
    const int tx = tid & 15;        // col group: cols tx*8 .. tx*8+7
    const int ty = tid >> 4;        // row group: rows ty*8 .. ty*8+7
    const int c8 = tx * 8;
    const int r0 = ty * 8;
    const int brow = blockIdx.x * 128;

    float4 acc[8][2];
    #pragma unroll
    for (int i = 0; i < 8; i++) {
        acc[i][0] = make_float4(0.f, 0.f, 0.f, 0.f);
        acc[i][1] = make_float4(0.f, 0.f, 0.f, 0.f);
    }

    const int lar = tid >> 3;        // 0..31  (row within 32-row slab)
    const int lac = (tid & 7) * 4;   // 0..28  (k offset)

    for (int kt = 0; kt < 128; kt += 32) {
        #pragma unroll
        for (int p = 0; p < 4; p++) {
            int row = brow + lar + p * 32;
            float4 v = (row < M) ? *(const float4*)(A + (size_t)row * HIDDIM + kt + lac)
                                 : make_float4(0.f, 0.f, 0.f, 0.f);
            Ast[lac + 0][lar + p * 32] = v.x;
            Ast[lac + 1][lar + p * 32] = v.y;
            Ast[lac + 2][lar + p * 32] = v.z;
            Ast[lac + 3][lar + p * 32] = v.w;
        }
        {
            int c4 = (tid & 31) * 4;
            int rb0 = tid >> 5;
            #pragma unroll
            for (int i = 0; i < 4; i++) {
                int rb = rb0 + i * 8;
                *(float4*)(&Bs[rb][c4]) = *(const float4*)(B + (size_t)(kt + rb) * HIDDIM + c4);
            }
        }
        __syncthreads();
        #pragma unroll 8
        for (int k = 0; k < 32; k++) {
            float4 a0 = *(float4*)(&Ast[k][r0]);
            float4 a1 = *(float4*)(&Ast[k][r0 + 4]);
            float4 b0 = *(float4*)(&Bs[k][c8]);
            float4 b1 = *(float4*)(&Bs[k][c8 + 4]);
            float ar[8] = {a0.x, a0.y, a0.z, a0.w, a1.x, a1.y, a1.z, a1.w};
            #pragma unroll
            for (int i = 0; i < 8; i++) {
                acc[i][0].x += ar[i] * b0.x; acc[i][0].y += ar[i] * b0.y;
                acc[i][0].z += ar[i] * b0.z; acc[i][0].w += ar[i] * b0.w;
                acc[i][1].x += ar[i] * b1.x; acc[i][1].y += ar[i] * b1.y;
                acc[i][1].z += ar[i] * b1.z; acc[i][1].w += ar[i] * b1.w;
            }
        }
        __syncthreads();
    }
    #pragma unroll
    for (int i = 0; i < 8; i++) {
        int row = brow + r0 + i;
        if (row < M) {
            union { __half2 h2[4]; uint4 u; } pk;
            pk.h2[0] = __floats2half2_rn(acc[i][0].x, acc[i][0].y);
            pk.h2[1] = __floats2half2_rn(acc[i][0].z, acc[i][0].w);
            pk.h2[2] = __floats2half2_rn(acc[i][1].x, acc[i][1].y);
            pk.h2[3] = __floats2half2_rn(acc[i][1].z, acc[i][1].w);
            *(uint4*)(C16 + (size_t)row * HIDDIM + c8) = pk.u;
        }
    }
}

// ---------------- attention logits (from fp16 h) ----------------

__global__ __launch_bounds__(256) void attn_k(const __half* __restrict__ h16,
                                              const float* __restrict__ att_src,
                                              const float* __restrict__ att_dst,
                                              float* __restrict__ aS, float* __restrict__ aD) {
    int lane = threadIdx.x & 63;
    int n = blockIdx.x * 4 + (threadIdx.x >> 6);
    if (n >= NNODES) return;
    int c2 = lane * 2;
    float2 hv = __half22float2(*(const __half2*)(h16 + (size_t)n * HIDDIM + c2));
    float ps = hv.x * att_src[c2] + hv.y * att_src[c2 + 1];
    float pd = hv.x * att_dst[c2] + hv.y * att_dst[c2 + 1];
    #pragma unroll
    for (int m = 1; m < 16; m <<= 1) {
        ps += __shfl_xor(ps, m);
        pd += __shfl_xor(pd, m);
    }
    if ((lane & 15) == 0) {
        aS[n * NHEAD + (lane >> 4)] = ps;
        aD[n * NHEAD + (lane >> 4)] = pd;
    }
}

// ---------------- aggregate: one wave per dst node, 4 edges in flight ----------------
// lane = slot*16 + cg; slot in [0,4) = concurrent edge slot, cg in [0,16) = 8-channel
// group (16B fp16 load). Cross-slot reduce via shfl_xor(16,32) at the end.

__global__ __launch_bounds__(256) void agg_k(const __half* __restrict__ h16,
                                             const int* __restrict__ offs,
                                             const int* __restrict__ deg,
                                             const int* __restrict__ srcs,
                                             const float* __restrict__ aS,
                                             const float* __restrict__ aD,
                                             const float* __restrict__ bias,
                                             float* __restrict__ out) {
    int lane = threadIdx.x & 63;
    int n = blockIdx.x * 4 + (threadIdx.x >> 6);
    if (n >= NNODES) return;
    int slot = lane >> 4;
    int cg = lane & 15;
    int c8 = cg * 8;
    int head = cg >> 2;
    int start = offs[n];
    int cnt = deg[n];
    float ad = aD[n * NHEAD + head];
    float acc[8] = {0.f, 0.f, 0.f, 0.f, 0.f, 0.f, 0.f, 0.f};
    float wsum = 0.f;

    for (int base = 0; base < cnt; base += 4) {
        int ei = base + slot;
        bool valid = ei < cnt;
        int s = srcs[start + (valid ? ei : 0)];
        if (valid) {
            float e = aS[s * NHEAD + head] + ad;
            e = (e > 0.f) ? e : 0.2f * e;
            float w = __expf(e);
            union { uint4 u; __half2 h2[4]; } hv;
            hv.u = *(const uint4*)(h16 + (size_t)s * HIDDIM + c8);
            #pragma unroll
            for (int i = 0; i < 4; i++) {
                float2 f = __half22float2(hv.h2[i]);
                acc[2 * i]     += w * f.x;
                acc[2 * i + 1] += w * f.y;
            }
            wsum += w;
        }
    }

    #pragma unroll
    for (int m = 16; m < 64; m <<= 1) {
        wsum += __shfl_xor(wsum, m);
        #pragma unroll
        for (int i = 0; i < 8; i++) acc[i] += __shfl_xor(acc[i], m);
    }

    if (slot == 0) {
        float inv = 1.f / (wsum + 1e-16f);
        float4 v0, v1;
        v0.x = acc[0] * inv + bias[c8 + 0];
        v0.y = acc[1] * inv + bias[c8 + 1];
        v0.z = acc[2] * inv + bias[c8 + 2];
        v0.w = acc[3] * inv + bias[c8 + 3];
        v1.x = acc[4] * inv + bias[c8 + 4];
        v1.y = acc[5] * inv + bias[c8 + 5];
        v1.z = acc[6] * inv + bias[c8 + 6];
        v1.w = acc[7] * inv + bias[c8 + 7];
        v0.x = v0.x > 0.f ? v0.x : 0.f; v0.y = v0.y > 0.f ? v0.y : 0.f;
        v0.z = v0.z > 0.f ? v0.z : 0.f; v0.w = v0.w > 0.f ? v0.w : 0.f;
        v1.x = v1.x > 0.f ? v1.x : 0.f; v1.y = v1.y > 0.f ? v1.y : 0.f;
        v1.z = v1.z > 0.f ? v1.z : 0.f; v1.w = v1.w > 0.f ? v1.w : 0.f;
        *(float4*)(out + (size_t)n * HIDDIM + c8) = v0;
        *(float4*)(out + (size_t)n * HIDDIM + c8 + 4) = v1;
    }
}

// ---------------- launch ----------------

extern "C" void kernel_launch(void* const* d_in, const int* in_sizes, int n_in,
                              void* d_out, int out_size, void* d_ws, size_t ws_size,
                              hipStream_t stream) {
    (void)in_sizes; (void)n_in; (void)out_size; (void)ws_size;
    const float* x = (const float*)d_in[0];

    char* ws = (char*)d_ws;
    size_t off = 0;
    auto alloc = [&](size_t bytes) -> void* {
        void* p = ws + off;
        off += (bytes + 255) & ~(size_t)255;
        return p;
    };
    float* bufA   = (float*)alloc((size_t)NNODES * HIDDIM * 4);   // layer outputs (fp32)
    __half* h16   = (__half*)alloc((size_t)NNODES * HIDDIM * 2);  // fp16 h
    float* aS     = (float*)alloc((size_t)NNODES * NHEAD * 4);
    float* aD     = (float*)alloc((size_t)NNODES * NHEAD * 4);
    int* deg      = (int*)alloc((size_t)NNODES * 4);
    int* offsArr  = (int*)alloc((size_t)NNODES * 4);
    int* cursor   = (int*)alloc((size_t)NNODES * 4);
    int* srcs     = (int*)alloc((size_t)(NEDGES + NNODES) * 4);
    int* blkSums  = (int*)alloc(128 * 4);

    const int nScan = (NNODES + 1023) / 1024;  // 98
    const float* in_ptr = x;
    for (int l = 0; l < 3; l++) {
        const int* ei      = (const int*)d_in[1 + 5 * l];
        const float* Wm    = (const float*)d_in[2 + 5 * l];
        const float* attS  = (const float*)d_in[3 + 5 * l];
        const float* attD  = (const float*)d_in[4 + 5 * l];
        const float* biasv = (const float*)d_in[5 + 5 * l];
        const int* srcRow = ei;
        const int* dstRow = ei + NEDGES;
        // l0,l1 out -> bufA (input already consumed by gemm before agg writes);
        // l2 out -> d_out.
        float* outp = (l == 2) ? (float*)d_out : bufA;

        hipLaunchKernelGGL(init_deg_k, dim3((NNODES + 255) / 256), dim3(256), 0, stream, deg);
        hipLaunchKernelGGL(hist_k, dim3((NEDGES + 255) / 256), dim3(256), 0, stream, dstRow, deg);
        hipLaunchKernelGGL(scan1_k, dim3(nScan), dim3(1024), 0, stream, deg, offsArr, blkSums);
        hipLaunchKernelGGL(scan2_k, dim3(1), dim3(128), 0, stream, blkSums, nScan);
        hipLaunchKernelGGL(scan3_k, dim3(nScan), dim3(1024), 0, stream, offsArr, blkSums, cursor);
        hipLaunchKernelGGL(scatter_k, dim3((NEDGES + NNODES + 255) / 256), dim3(256), 0, stream,
                           srcRow, dstRow, cursor, srcs);
        hipLaunchKernelGGL(gemm_k, dim3((NNODES + 127) / 128), dim3(256), 0, stream,
                           in_ptr, Wm, h16, NNODES);
        hipLaunchKernelGGL(attn_k, dim3((NNODES + 3) / 4), dim3(256), 0, stream,
                           h16, attS, attD, aS, aD);
        hipLaunchKernelGGL(agg_k, dim3((NNODES + 3) / 4), dim3(256), 0, stream,
                           h16, offsArr, deg, srcs, aS, aD, biasv, outp);
        in_ptr = outp;
    }
}

// Round 4
// 570.417 us; speedup vs baseline: 1.5769x; 1.3231x over previous
//
#include <hip/hip_runtime.h>
#include <hip/hip_bf16.h>
#include <hip/hip_fp16.h>
#include <type_traits>

#define NNODES 100000
#define NEDGES 800000
#define HIDDIM 128
#define NHEAD 4

typedef _Float16 half8 __attribute__((ext_vector_type(8)));
typedef float floatx4 __attribute__((ext_vector_type(4)));

// ---------------- CSR build ----------------

__global__ void init_deg_k(int* __restrict__ deg) {
    int i = blockIdx.x * blockDim.x + threadIdx.x;
    if (i < NNODES) deg[i] = 0;
}

// histogram + per-edge rank (return value of the atomic)
__global__ void hist_k(const int* __restrict__ dst, int* __restrict__ deg,
                       int* __restrict__ rank) {
    int e = blockIdx.x * blockDim.x + threadIdx.x;
    if (e < NEDGES) rank[e] = atomicAdd(&deg[dst[e]], 1);
}

__global__ void scan1_k(const int* __restrict__ deg, int* __restrict__ offs,
                        int* __restrict__ blkSums) {
    __shared__ int sd[1024];
    int t = threadIdx.x;
    int i = blockIdx.x * 1024 + t;
    int v = (i < NNODES) ? (deg[i] + 1) : 0;  // +1: self-loop slot
    sd[t] = v;
    __syncthreads();
    for (int off = 1; off < 1024; off <<= 1) {
        int tv = (t >= off) ? sd[t - off] : 0;
        __syncthreads();
        sd[t] += tv;
        __syncthreads();
    }
    if (i < NNODES) offs[i] = sd[t] - v;  // exclusive within block
    if (t == 1023) blkSums[blockIdx.x] = sd[1023];
}

__global__ void scan2_k(int* __restrict__ blkSums, int nb) {
    __shared__ int sd[128];
    int t = threadIdx.x;
    int v = (t < nb) ? blkSums[t] : 0;
    sd[t] = v;
    __syncthreads();
    for (int off = 1; off < 128; off <<= 1) {
        int tv = (t >= off) ? sd[t - off] : 0;
        __syncthreads();
        sd[t] += tv;
        __syncthreads();
    }
    if (t < nb) blkSums[t] = sd[t] - v;
}

__global__ void scan3_k(int* __restrict__ offs, const int* __restrict__ blkSums) {
    int i = blockIdx.x * 1024 + threadIdx.x;
    if (i < NNODES) offs[i] += blkSums[blockIdx.x];
}

// atomic-free scatter: pos = offs[dst] + rank
__global__ void scatter_k(const int* __restrict__ srcRow, const int* __restrict__ dstRow,
                          const int* __restrict__ rank, const int* __restrict__ offs,
                          const int* __restrict__ deg, int* __restrict__ srcs) {
    int t = blockIdx.x * blockDim.x + threadIdx.x;
    if (t < NEDGES) {
        int d = dstRow[t];
        srcs[offs[d] + rank[t]] = srcRow[t];
    } else if (t < NEDGES + NNODES) {
        int n = t - NEDGES;
        srcs[offs[n] + deg[n]] = n;  // self-loop in last slot
    }
}

// ---------------- GEMM via MFMA: h16[M,128] = fp16(A[M,128] @ B[128,128]) ----------------
// 256 threads = 4 waves; 256 rows/block (4 iters x 64 rows).
// B transposed to fp16 LDS once, all 32 B-frags hoisted to registers.
// mfma_f32_16x16x32_f16: A[m=lane&15][k=quad*8+j]; B[k=quad*8+j][n=lane&15];
// D: col=lane&15, row=quad*4+reg.

template <typename AT>
__global__ __launch_bounds__(256, 2) void gemm_mfma_k(const AT* __restrict__ A,
                                                      const float* __restrict__ B,
                                                      __half* __restrict__ C16, int M) {
    __shared__ __half Bt[128 * 136];  // Bt[n][k], stride 136 breaks bank conflicts
    const int tid = threadIdx.x;
    // stage B transposed as fp16
    {
        int kk = (tid & 63) * 2;
        int g = tid >> 6;
        #pragma unroll
        for (int jn = 0; jn < 8; jn++) {
            int n0 = g * 4 + jn * 16;
            float4 r0 = *(const float4*)(B + (size_t)kk * 128 + n0);
            float4 r1 = *(const float4*)(B + (size_t)(kk + 1) * 128 + n0);
            float f0[4] = {r0.x, r0.y, r0.z, r0.w};
            float f1[4] = {r1.x, r1.y, r1.z, r1.w};
            #pragma unroll
            for (int i = 0; i < 4; i++)
                *(__half2*)(&Bt[(n0 + i) * 136 + kk]) = __floats2half2_rn(f0[i], f1[i]);
        }
    }
    __syncthreads();

    const int lane = tid & 63;
    const int wave = tid >> 6;
    const int m = lane & 15;
    const int q = lane >> 4;

    half8 bfrag[8][4];
    #pragma unroll
    for (int c = 0; c < 8; c++)
        #pragma unroll
        for (int t = 0; t < 4; t++)
            bfrag[c][t] = *(const half8*)(&Bt[(c * 16 + m) * 136 + t * 32 + q * 8]);

    for (int iter = 0; iter < 4; iter++) {
        int rb = blockIdx.x * 256 + iter * 64 + wave * 16;  // wave-uniform
        if (rb >= M) break;
        int row = rb + m;
        int rowc = row < M ? row : M - 1;
        half8 a[4];
        if constexpr (std::is_same<AT, __half>::value) {
            const __half* ap = A + (size_t)rowc * HIDDIM;
            #pragma unroll
            for (int t = 0; t < 4; t++)
                a[t] = *(const half8*)(ap + t * 32 + q * 8);
        } else {
            const float* ap = A + (size_t)rowc * HIDDIM;
            #pragma unroll
            for (int t = 0; t < 4; t++) {
                float4 u = *(const float4*)(ap + t * 32 + q * 8);
                float4 v = *(const float4*)(ap + t * 32 + q * 8 + 4);
                half8 h;
                h[0] = (_Float16)u.x; h[1] = (_Float16)u.y;
                h[2] = (_Float16)u.z; h[3] = (_Float16)u.w;
                h[4] = (_Float16)v.x; h[5] = (_Float16)v.y;
                h[6] = (_Float16)v.z; h[7] = (_Float16)v.w;
                a[t] = h;
            }
        }
        floatx4 acc[8];
        #pragma unroll
        for (int c = 0; c < 8; c++) acc[c] = (floatx4){0.f, 0.f, 0.f, 0.f};
        #pragma unroll
        for (int t = 0; t < 4; t++)
            #pragma unroll
            for (int c = 0; c < 8; c++)
                acc[c] = __builtin_amdgcn_mfma_f32_16x16x32_f16(a[t], bfrag[c][t], acc[c], 0, 0, 0);
        #pragma unroll
        for (int c = 0; c < 8; c++)
            #pragma unroll
            for (int r = 0; r < 4; r++) {
                int grow = rb + q * 4 + r;
                if (grow < M)
                    C16[(size_t)grow * HIDDIM + c * 16 + m] = __float2half(acc[c][r]);
            }
    }
}

// ---------------- attention logits (from fp16 h) ----------------

__global__ __launch_bounds__(256) void attn_k(const __half* __restrict__ h16,
                                              const float* __restrict__ att_src,
                                              const float* __restrict__ att_dst,
                                              float* __restrict__ aS, float* __restrict__ aD) {
    int lane = threadIdx.x & 63;
    int n = blockIdx.x * 4 + (threadIdx.x >> 6);
    if (n >= NNODES) return;
    int c2 = lane * 2;
    float2 hv = __half22float2(*(const __half2*)(h16 + (size_t)n * HIDDIM + c2));
    float ps = hv.x * att_src[c2] + hv.y * att_src[c2 + 1];
    float pd = hv.x * att_dst[c2] + hv.y * att_dst[c2 + 1];
    #pragma unroll
    for (int m = 1; m < 16; m <<= 1) {
        ps += __shfl_xor(ps, m);
        pd += __shfl_xor(pd, m);
    }
    if ((lane & 15) == 0) {
        aS[n * NHEAD + (lane >> 4)] = ps;
        aD[n * NHEAD + (lane >> 4)] = pd;
    }
}

// ---------------- aggregate: one wave per dst node, 4 edges in flight ----------------

template <bool HALF_OUT>
__global__ __launch_bounds__(256) void agg_k(const __half* __restrict__ h16,
                                             const int* __restrict__ offs,
                                             const int* __restrict__ deg,
                                             const int* __restrict__ srcs,
                                             const float* __restrict__ aS,
                                             const float* __restrict__ aD,
                                             const float* __restrict__ bias,
                                             void* __restrict__ outv) {
    int lane = threadIdx.x & 63;
    int n = blockIdx.x * 4 + (threadIdx.x >> 6);
    if (n >= NNODES) return;
    int slot = lane >> 4;
    int cg = lane & 15;
    int c8 = cg * 8;
    int head = cg >> 2;
    int start = offs[n];
    int cnt = deg[n] + 1;
    float ad = aD[n * NHEAD + head];
    float acc[8] = {0.f, 0.f, 0.f, 0.f, 0.f, 0.f, 0.f, 0.f};
    float wsum = 0.f;

    for (int base = 0; base < cnt; base += 4) {
        int ei = base + slot;
        bool valid = ei < cnt;
        int s = srcs[start + (valid ? ei : 0)];
        if (valid) {
            float e = aS[s * NHEAD + head] + ad;
            e = (e > 0.f) ? e : 0.2f * e;
            float w = __expf(e);
            union { uint4 u; __half2 h2[4]; } hv;
            hv.u = *(const uint4*)(h16 + (size_t)s * HIDDIM + c8);
            #pragma unroll
            for (int i = 0; i < 4; i++) {
                float2 f = __half22float2(hv.h2[i]);
                acc[2 * i]     += w * f.x;
                acc[2 * i + 1] += w * f.y;
            }
            wsum += w;
        }
    }

    #pragma unroll
    for (int m = 16; m < 64; m <<= 1) {
        wsum += __shfl_xor(wsum, m);
        #pragma unroll
        for (int i = 0; i < 8; i++) acc[i] += __shfl_xor(acc[i], m);
    }

    if (slot == 0) {
        float inv = 1.f / (wsum + 1e-16f);
        float v[8];
        #pragma unroll
        for (int i = 0; i < 8; i++) {
            float o = acc[i] * inv + bias[c8 + i];
            v[i] = o > 0.f ? o : 0.f;
        }
        if constexpr (HALF_OUT) {
            union { uint4 u; __half2 h2[4]; } pk;
            #pragma unroll
            for (int i = 0; i < 4; i++) pk.h2[i] = __floats2half2_rn(v[2 * i], v[2 * i + 1]);
            *(uint4*)((__half*)outv + (size_t)n * HIDDIM + c8) = pk.u;
        } else {
            float* out = (float*)outv;
            *(float4*)(out + (size_t)n * HIDDIM + c8) = make_float4(v[0], v[1], v[2], v[3]);
            *(float4*)(out + (size_t)n * HIDDIM + c8 + 4) = make_float4(v[4], v[5], v[6], v[7]);
        }
    }
}

// ---------------- launch ----------------

extern "C" void kernel_launch(void* const* d_in, const int* in_sizes, int n_in,
                              void* d_out, int out_size, void* d_ws, size_t ws_size,
                              hipStream_t stream) {
    (void)in_sizes; (void)n_in; (void)out_size; (void)ws_size;
    const float* x = (const float*)d_in[0];

    char* ws = (char*)d_ws;
    size_t off = 0;
    auto alloc = [&](size_t bytes) -> void* {
        void* p = ws + off;
        off += (bytes + 255) & ~(size_t)255;
        return p;
    };
    __half* xh    = (__half*)alloc((size_t)NNODES * HIDDIM * 2);  // fp16 layer in/out
    __half* h16   = (__half*)alloc((size_t)NNODES * HIDDIM * 2);  // fp16 h
    float* aS     = (float*)alloc((size_t)NNODES * NHEAD * 4);
    float* aD     = (float*)alloc((size_t)NNODES * NHEAD * 4);
    int* deg      = (int*)alloc((size_t)NNODES * 4);
    int* offsArr  = (int*)alloc((size_t)NNODES * 4);
    int* rankArr  = (int*)alloc((size_t)NEDGES * 4);
    int* srcs     = (int*)alloc((size_t)(NEDGES + NNODES) * 4);
    int* blkSums  = (int*)alloc(128 * 4);

    const int nScan = (NNODES + 1023) / 1024;  // 98
    for (int l = 0; l < 3; l++) {
        const int* ei      = (const int*)d_in[1 + 5 * l];
        const float* Wm    = (const float*)d_in[2 + 5 * l];
        const float* attS  = (const float*)d_in[3 + 5 * l];
        const float* attD  = (const float*)d_in[4 + 5 * l];
        const float* biasv = (const float*)d_in[5 + 5 * l];
        const int* srcRow = ei;
        const int* dstRow = ei + NEDGES;

        hipLaunchKernelGGL(init_deg_k, dim3((NNODES + 255) / 256), dim3(256), 0, stream, deg);
        hipLaunchKernelGGL(hist_k, dim3((NEDGES + 255) / 256), dim3(256), 0, stream,
                           dstRow, deg, rankArr);
        hipLaunchKernelGGL(scan1_k, dim3(nScan), dim3(1024), 0, stream, deg, offsArr, blkSums);
        hipLaunchKernelGGL(scan2_k, dim3(1), dim3(128), 0, stream, blkSums, nScan);
        hipLaunchKernelGGL(scan3_k, dim3(nScan), dim3(1024), 0, stream, offsArr, blkSums);
        hipLaunchKernelGGL(scatter_k, dim3((NEDGES + NNODES + 255) / 256), dim3(256), 0, stream,
                           srcRow, dstRow, rankArr, offsArr, deg, srcs);
        if (l == 0) {
            hipLaunchKernelGGL((gemm_mfma_k<float>), dim3((NNODES + 255) / 256), dim3(256), 0,
                               stream, x, Wm, h16, NNODES);
        } else {
            hipLaunchKernelGGL((gemm_mfma_k<__half>), dim3((NNODES + 255) / 256), dim3(256), 0,
                               stream, xh, Wm, h16, NNODES);
        }
        hipLaunchKernelGGL(attn_k, dim3((NNODES + 3) / 4), dim3(256), 0, stream,
                           h16, attS, attD, aS, aD);
        if (l == 2) {
            hipLaunchKernelGGL((agg_k<false>), dim3((NNODES + 3) / 4), dim3(256), 0, stream,
                               h16, offsArr, deg, srcs, aS, aD, biasv, d_out);
        } else {
            // xh was fully consumed by this layer's gemm before agg runs (stream order)
            hipLaunchKernelGGL((agg_k<true>), dim3((NNODES + 3) / 4), dim3(256), 0, stream,
                               h16, offsArr, deg, srcs, aS, aD, biasv, (void*)xh);
        }
    }
}

// Round 5
// 552.331 us; speedup vs baseline: 1.6285x; 1.0327x over previous
//
#include <hip/hip_runtime.h>
#include <hip/hip_bf16.h>
#include <hip/hip_fp16.h>
#include <type_traits>

#define NNODES 100000
#define NEDGES 800000
#define HIDDIM 128
#define NHEAD 4

typedef _Float16 half8 __attribute__((ext_vector_type(8)));
typedef _Float16 half2t __attribute__((ext_vector_type(2)));
typedef float floatx4 __attribute__((ext_vector_type(4)));

// ---------------- CSR build ----------------

// histogram + per-edge rank (return value of the atomic)
__global__ void hist_k(const int* __restrict__ dst, int* __restrict__ deg,
                       int* __restrict__ rank) {
    int e = blockIdx.x * blockDim.x + threadIdx.x;
    if (e < NEDGES) rank[e] = atomicAdd(&deg[dst[e]], 1);
}

__global__ void scan1_k(const int* __restrict__ deg, int* __restrict__ offs,
                        int* __restrict__ blkSums) {
    __shared__ int sd[1024];
    int t = threadIdx.x;
    int i = blockIdx.x * 1024 + t;
    int v = (i < NNODES) ? (deg[i] + 1) : 0;  // +1: self-loop slot
    sd[t] = v;
    __syncthreads();
    for (int off = 1; off < 1024; off <<= 1) {
        int tv = (t >= off) ? sd[t - off] : 0;
        __syncthreads();
        sd[t] += tv;
        __syncthreads();
    }
    if (i < NNODES) offs[i] = sd[t] - v;  // exclusive within block
    if (t == 1023) blkSums[blockIdx.x] = sd[1023];
}

__global__ void scan2_k(int* __restrict__ blkSums, int nb) {
    __shared__ int sd[128];
    int t = threadIdx.x;
    int v = (t < nb) ? blkSums[t] : 0;
    sd[t] = v;
    __syncthreads();
    for (int off = 1; off < 128; off <<= 1) {
        int tv = (t >= off) ? sd[t - off] : 0;
        __syncthreads();
        sd[t] += tv;
        __syncthreads();
    }
    if (t < nb) blkSums[t] = sd[t] - v;
}

__global__ void scan3_k(int* __restrict__ offs, const int* __restrict__ blkSums) {
    int i = blockIdx.x * 1024 + threadIdx.x;
    if (i < NNODES) offs[i] += blkSums[blockIdx.x];
}

// XCD-range-partitioned scatter: group g (= blockIdx&7, XCD round-robin heuristic)
// only writes dst in [g*12500, (g+1)*12500) so each srcs cache line is dirtied by
// a single XCD -> full-line evictions instead of 16x partial-line amplification.
__global__ __launch_bounds__(256) void scatter_k(const int* __restrict__ srcRow,
                                                 const int* __restrict__ dstRow,
                                                 const int* __restrict__ rank,
                                                 const int* __restrict__ offs,
                                                 const int* __restrict__ deg,
                                                 int* __restrict__ srcs) {
    int group = blockIdx.x & 7;
    int t = (blockIdx.x >> 3) * 256 + threadIdx.x;
    int lo = group * (NNODES / 8);
    int hi = lo + (NNODES / 8);
    if (t < NEDGES) {
        int d = dstRow[t];
        if (d >= lo && d < hi) srcs[offs[d] + rank[t]] = srcRow[t];
    } else if (t < NEDGES + NNODES) {
        int n = t - NEDGES;
        if (n >= lo && n < hi) srcs[offs[n] + deg[n]] = n;  // self-loop in last slot
    }
}

// ---------------- GEMM via MFMA: h16[M,128] = fp16(A[M,128] @ B[128,128]) ----------------

template <typename AT>
__global__ __launch_bounds__(256, 2) void gemm_mfma_k(const AT* __restrict__ A,
                                                      const float* __restrict__ B,
                                                      __half* __restrict__ C16, int M) {
    __shared__ __half Bt[128 * 136];  // Bt[n][k], stride 136 breaks bank conflicts
    const int tid = threadIdx.x;
    {
        int kk = (tid & 63) * 2;
        int g = tid >> 6;
        #pragma unroll
        for (int jn = 0; jn < 8; jn++) {
            int n0 = g * 4 + jn * 16;
            float4 r0 = *(const float4*)(B + (size_t)kk * 128 + n0);
            float4 r1 = *(const float4*)(B + (size_t)(kk + 1) * 128 + n0);
            float f0[4] = {r0.x, r0.y, r0.z, r0.w};
            float f1[4] = {r1.x, r1.y, r1.z, r1.w};
            #pragma unroll
            for (int i = 0; i < 4; i++)
                *(__half2*)(&Bt[(n0 + i) * 136 + kk]) = __floats2half2_rn(f0[i], f1[i]);
        }
    }
    __syncthreads();

    const int lane = tid & 63;
    const int wave = tid >> 6;
    const int m = lane & 15;
    const int q = lane >> 4;

    half8 bfrag[8][4];
    #pragma unroll
    for (int c = 0; c < 8; c++)
        #pragma unroll
        for (int t = 0; t < 4; t++)
            bfrag[c][t] = *(const half8*)(&Bt[(c * 16 + m) * 136 + t * 32 + q * 8]);

    for (int iter = 0; iter < 4; iter++) {
        int rb = blockIdx.x * 256 + iter * 64 + wave * 16;  // wave-uniform
        if (rb >= M) break;
        int row = rb + m;
        int rowc = row < M ? row : M - 1;
        half8 a[4];
        if constexpr (std::is_same<AT, __half>::value) {
            const __half* ap = A + (size_t)rowc * HIDDIM;
            #pragma unroll
            for (int t = 0; t < 4; t++)
                a[t] = *(const half8*)(ap + t * 32 + q * 8);
        } else {
            const float* ap = A + (size_t)rowc * HIDDIM;
            #pragma unroll
            for (int t = 0; t < 4; t++) {
                float4 u = *(const float4*)(ap + t * 32 + q * 8);
                float4 v = *(const float4*)(ap + t * 32 + q * 8 + 4);
                half8 h;
                h[0] = (_Float16)u.x; h[1] = (_Float16)u.y;
                h[2] = (_Float16)u.z; h[3] = (_Float16)u.w;
                h[4] = (_Float16)v.x; h[5] = (_Float16)v.y;
                h[6] = (_Float16)v.z; h[7] = (_Float16)v.w;
                a[t] = h;
            }
        }
        floatx4 acc[8];
        #pragma unroll
        for (int c = 0; c < 8; c++) acc[c] = (floatx4){0.f, 0.f, 0.f, 0.f};
        #pragma unroll
        for (int t = 0; t < 4; t++)
            #pragma unroll
            for (int c = 0; c < 8; c++)
                acc[c] = __builtin_amdgcn_mfma_f32_16x16x32_f16(a[t], bfrag[c][t], acc[c], 0, 0, 0);
        #pragma unroll
        for (int c = 0; c < 8; c++)
            #pragma unroll
            for (int r = 0; r < 4; r++) {
                int grow = rb + q * 4 + r;
                if (grow < M)
                    C16[(size_t)grow * HIDDIM + c * 16 + m] = __float2half(acc[c][r]);
            }
    }
}

// ---------------- attention logits (from fp16 h) ----------------

__global__ __launch_bounds__(256) void attn_k(const __half* __restrict__ h16,
                                              const float* __restrict__ att_src,
                                              const float* __restrict__ att_dst,
                                              float* __restrict__ aS, float* __restrict__ aD) {
    int lane = threadIdx.x & 63;
    int n = blockIdx.x * 4 + (threadIdx.x >> 6);
    if (n >= NNODES) return;
    int c2 = lane * 2;
    float2 hv = __half22float2(*(const __half2*)(h16 + (size_t)n * HIDDIM + c2));
    float ps = hv.x * att_src[c2] + hv.y * att_src[c2 + 1];
    float pd = hv.x * att_dst[c2] + hv.y * att_dst[c2 + 1];
    #pragma unroll
    for (int m = 1; m < 16; m <<= 1) {
        ps += __shfl_xor(ps, m);
        pd += __shfl_xor(pd, m);
    }
    if ((lane & 15) == 0) {
        aS[n * NHEAD + (lane >> 4)] = ps;
        aD[n * NHEAD + (lane >> 4)] = pd;
    }
}

// ---------------- aggregate: one wave per dst node, 4 edges in flight ----------------
// srcs prefetched 64 at a time (one coalesced load, shfl broadcast in loop);
// accumulation in packed fp16 (v_pk_fma_f16), wsum in fp32.

template <bool HALF_OUT>
__global__ __launch_bounds__(256) void agg_k(const __half* __restrict__ h16,
                                             const int* __restrict__ offs,
                                             const int* __restrict__ deg,
                                             const int* __restrict__ srcs,
                                             const float* __restrict__ aS,
                                             const float* __restrict__ aD,
                                             const float* __restrict__ bias,
                                             void* __restrict__ outv) {
    int lane = threadIdx.x & 63;
    int n = blockIdx.x * 4 + (threadIdx.x >> 6);
    if (n >= NNODES) return;
    int slot = lane >> 4;
    int cg = lane & 15;
    int c8 = cg * 8;
    int head = cg >> 2;
    int start = offs[n];
    int cnt = deg[n] + 1;
    float ad = aD[n * NHEAD + head];
    half2t acc[4];
    #pragma unroll
    for (int i = 0; i < 4; i++) acc[i] = (half2t){(_Float16)0.f, (_Float16)0.f};
    float wsum = 0.f;

    for (int chunk = 0; chunk < cnt; chunk += 64) {
        int idx = chunk + lane;
        int sv = srcs[start + (idx < cnt ? idx : 0)];
        int lim = min(64, cnt - chunk);
        for (int b = 0; b < lim; b += 4) {
            int ei = b + slot;
            bool valid = ei < lim;
            int s = __shfl(sv, b + slot);
            if (valid) {
                float e = aS[s * NHEAD + head] + ad;
                e = (e > 0.f) ? e : 0.2f * e;
                float w = __expf(e);
                wsum += w;
                _Float16 wh = (_Float16)w;
                half2t w2 = (half2t){wh, wh};
                half8 hv = *(const half8*)(h16 + (size_t)s * HIDDIM + c8);
                #pragma unroll
                for (int i = 0; i < 4; i++) {
                    half2t hp = (half2t){hv[2 * i], hv[2 * i + 1]};
                    acc[i] += w2 * hp;
                }
            }
        }
    }

    #pragma unroll
    for (int m = 16; m < 64; m <<= 1) {
        wsum += __shfl_xor(wsum, m);
        #pragma unroll
        for (int i = 0; i < 4; i++) {
            union { half2t h; int v; } u;
            u.h = acc[i];
            u.v = __shfl_xor(u.v, m);
            acc[i] += u.h;
        }
    }

    if (slot == 0) {
        float inv = 1.f / (wsum + 1e-16f);
        float v[8];
        #pragma unroll
        for (int i = 0; i < 4; i++) {
            float o0 = (float)acc[i][0] * inv + bias[c8 + 2 * i];
            float o1 = (float)acc[i][1] * inv + bias[c8 + 2 * i + 1];
            v[2 * i] = o0 > 0.f ? o0 : 0.f;
            v[2 * i + 1] = o1 > 0.f ? o1 : 0.f;
        }
        if constexpr (HALF_OUT) {
            union { uint4 u; __half2 h2[4]; } pk;
            #pragma unroll
            for (int i = 0; i < 4; i++) pk.h2[i] = __floats2half2_rn(v[2 * i], v[2 * i + 1]);
            *(uint4*)((__half*)outv + (size_t)n * HIDDIM + c8) = pk.u;
        } else {
            float* out = (float*)outv;
            *(float4*)(out + (size_t)n * HIDDIM + c8) = make_float4(v[0], v[1], v[2], v[3]);
            *(float4*)(out + (size_t)n * HIDDIM + c8 + 4) = make_float4(v[4], v[5], v[6], v[7]);
        }
    }
}

// ---------------- launch ----------------

extern "C" void kernel_launch(void* const* d_in, const int* in_sizes, int n_in,
                              void* d_out, int out_size, void* d_ws, size_t ws_size,
                              hipStream_t stream) {
    (void)in_sizes; (void)n_in; (void)out_size; (void)ws_size;
    const float* x = (const float*)d_in[0];

    char* ws = (char*)d_ws;
    size_t off = 0;
    auto alloc = [&](size_t bytes) -> void* {
        void* p = ws + off;
        off += (bytes + 255) & ~(size_t)255;
        return p;
    };
    __half* xh    = (__half*)alloc((size_t)NNODES * HIDDIM * 2);  // fp16 layer in/out
    __half* h16   = (__half*)alloc((size_t)NNODES * HIDDIM * 2);  // fp16 h
    float* aS     = (float*)alloc((size_t)NNODES * NHEAD * 4);
    float* aD     = (float*)alloc((size_t)NNODES * NHEAD * 4);
    int* deg      = (int*)alloc((size_t)NNODES * 4);
    int* offsArr  = (int*)alloc((size_t)NNODES * 4);
    int* rankArr  = (int*)alloc((size_t)NEDGES * 4);
    int* srcs     = (int*)alloc((size_t)(NEDGES + NNODES) * 4);
    int* blkSums  = (int*)alloc(128 * 4);

    const int nScan = (NNODES + 1023) / 1024;  // 98
    const int nScatBlk = ((NEDGES + NNODES + 255) / 256) * 8;
    for (int l = 0; l < 3; l++) {
        const int* ei      = (const int*)d_in[1 + 5 * l];
        const float* Wm    = (const float*)d_in[2 + 5 * l];
        const float* attS  = (const float*)d_in[3 + 5 * l];
        const float* attD  = (const float*)d_in[4 + 5 * l];
        const float* biasv = (const float*)d_in[5 + 5 * l];
        const int* srcRow = ei;
        const int* dstRow = ei + NEDGES;

        hipMemsetAsync(deg, 0, (size_t)NNODES * 4, stream);
        hipLaunchKernelGGL(hist_k, dim3((NEDGES + 255) / 256), dim3(256), 0, stream,
                           dstRow, deg, rankArr);
        hipLaunchKernelGGL(scan1_k, dim3(nScan), dim3(1024), 0, stream, deg, offsArr, blkSums);
        hipLaunchKernelGGL(scan2_k, dim3(1), dim3(128), 0, stream, blkSums, nScan);
        hipLaunchKernelGGL(scan3_k, dim3(nScan), dim3(1024), 0, stream, offsArr, blkSums);
        hipLaunchKernelGGL(scatter_k, dim3(nScatBlk), dim3(256), 0, stream,
                           srcRow, dstRow, rankArr, offsArr, deg, srcs);
        if (l == 0) {
            hipLaunchKernelGGL((gemm_mfma_k<float>), dim3((NNODES + 255) / 256), dim3(256), 0,
                               stream, x, Wm, h16, NNODES);
        } else {
            hipLaunchKernelGGL((gemm_mfma_k<__half>), dim3((NNODES + 255) / 256), dim3(256), 0,
                               stream, xh, Wm, h16, NNODES);
        }
        hipLaunchKernelGGL(attn_k, dim3((NNODES + 3) / 4), dim3(256), 0, stream,
                           h16, attS, attD, aS, aD);
        if (l == 2) {
            hipLaunchKernelGGL((agg_k<false>), dim3((NNODES + 3) / 4), dim3(256), 0, stream,
                               h16, offsArr, deg, srcs, aS, aD, biasv, d_out);
        } else {
            hipLaunchKernelGGL((agg_k<true>), dim3((NNODES + 3) / 4), dim3(256), 0, stream,
                               h16, offsArr, deg, srcs, aS, aD, biasv, (void*)xh);
        }
    }
}

// Round 6
// 540.714 us; speedup vs baseline: 1.6635x; 1.0215x over previous
//
#include <hip/hip_runtime.h>
#include <hip/hip_bf16.h>
#include <hip/hip_fp16.h>
#include <type_traits>

#define NNODES 100000
#define NEDGES 800000
#define HIDDIM 128
#define NHEAD 4

typedef _Float16 half8 __attribute__((ext_vector_type(8)));
typedef _Float16 half2t __attribute__((ext_vector_type(2)));
typedef float floatx4 __attribute__((ext_vector_type(4)));

// ---------------- CSR build ----------------

// histogram + per-edge rank (return value of the atomic)
__global__ void hist_k(const int* __restrict__ dst, int* __restrict__ deg,
                       int* __restrict__ rank) {
    int e = blockIdx.x * blockDim.x + threadIdx.x;
    if (e < NEDGES) rank[e] = atomicAdd(&deg[dst[e]], 1);
}

// block scan via wave shuffles: 2 barriers instead of 20
__global__ void scan1_k(const int* __restrict__ deg, int* __restrict__ offs,
                        int* __restrict__ blkSums) {
    __shared__ int wsums[16];
    int t = threadIdx.x;
    int lane = t & 63, wv = t >> 6;
    int i = blockIdx.x * 1024 + t;
    int v = (i < NNODES) ? (deg[i] + 1) : 0;  // +1: self-loop slot
    int x = v;
    #pragma unroll
    for (int off = 1; off < 64; off <<= 1) {
        int u = __shfl_up(x, off);
        if (lane >= off) x += u;
    }
    if (lane == 63) wsums[wv] = x;
    __syncthreads();
    if (t < 16) {
        int y = wsums[t];
        #pragma unroll
        for (int off = 1; off < 16; off <<= 1) {
            int u = __shfl_up(y, off);
            if (t >= off) y += u;
        }
        wsums[t] = y;  // inclusive wave sums
    }
    __syncthreads();
    int pre = (wv > 0) ? wsums[wv - 1] : 0;
    if (i < NNODES) offs[i] = pre + x - v;  // exclusive
    if (t == 1023) blkSums[blockIdx.x] = wsums[15];
}

__global__ void scan2_k(int* __restrict__ blkSums, int nb) {
    __shared__ int sd[128];
    int t = threadIdx.x;
    int v = (t < nb) ? blkSums[t] : 0;
    sd[t] = v;
    __syncthreads();
    for (int off = 1; off < 128; off <<= 1) {
        int tv = (t >= off) ? sd[t - off] : 0;
        __syncthreads();
        sd[t] += tv;
        __syncthreads();
    }
    if (t < nb) blkSums[t] = sd[t] - v;
}

__global__ void scan3_k(int* __restrict__ offs, const int* __restrict__ blkSums) {
    int i = blockIdx.x * 1024 + threadIdx.x;
    if (i < NNODES) offs[i] += blkSums[blockIdx.x];
}

// XCD-range-partitioned scatter (single-XCD line ownership for srcs writes)
__global__ __launch_bounds__(256) void scatter_k(const int* __restrict__ srcRow,
                                                 const int* __restrict__ dstRow,
                                                 const int* __restrict__ rank,
                                                 const int* __restrict__ offs,
                                                 const int* __restrict__ deg,
                                                 int* __restrict__ srcs) {
    int group = blockIdx.x & 7;
    int t = (blockIdx.x >> 3) * 256 + threadIdx.x;
    int lo = group * (NNODES / 8);
    int hi = lo + (NNODES / 8);
    if (t < NEDGES) {
        int d = dstRow[t];
        if (d >= lo && d < hi) srcs[offs[d] + rank[t]] = srcRow[t];
    } else if (t < NEDGES + NNODES) {
        int n = t - NEDGES;
        if (n >= lo && n < hi) srcs[offs[n] + deg[n]] = n;  // self-loop in last slot
    }
}

// ---------------- GEMM via MFMA: h16[M,128] = fp16(A[M,128] @ B[128,128]) ----------------

template <typename AT>
__global__ __launch_bounds__(256, 2) void gemm_mfma_k(const AT* __restrict__ A,
                                                      const float* __restrict__ B,
                                                      __half* __restrict__ C16, int M) {
    __shared__ __half Bt[128 * 136];  // Bt[n][k], stride 136 breaks bank conflicts
    const int tid = threadIdx.x;
    {
        int kk = (tid & 63) * 2;
        int g = tid >> 6;
        #pragma unroll
        for (int jn = 0; jn < 8; jn++) {
            int n0 = g * 4 + jn * 16;
            float4 r0 = *(const float4*)(B + (size_t)kk * 128 + n0);
            float4 r1 = *(const float4*)(B + (size_t)(kk + 1) * 128 + n0);
            float f0[4] = {r0.x, r0.y, r0.z, r0.w};
            float f1[4] = {r1.x, r1.y, r1.z, r1.w};
            #pragma unroll
            for (int i = 0; i < 4; i++)
                *(__half2*)(&Bt[(n0 + i) * 136 + kk]) = __floats2half2_rn(f0[i], f1[i]);
        }
    }
    __syncthreads();

    const int lane = tid & 63;
    const int wave = tid >> 6;
    const int m = lane & 15;
    const int q = lane >> 4;

    half8 bfrag[8][4];
    #pragma unroll
    for (int c = 0; c < 8; c++)
        #pragma unroll
        for (int t = 0; t < 4; t++)
            bfrag[c][t] = *(const half8*)(&Bt[(c * 16 + m) * 136 + t * 32 + q * 8]);

    for (int iter = 0; iter < 4; iter++) {
        int rb = blockIdx.x * 256 + iter * 64 + wave * 16;  // wave-uniform
        if (rb >= M) break;
        int row = rb + m;
        int rowc = row < M ? row : M - 1;
        half8 a[4];
        if constexpr (std::is_same<AT, __half>::value) {
            const __half* ap = A + (size_t)rowc * HIDDIM;
            #pragma unroll
            for (int t = 0; t < 4; t++)
                a[t] = *(const half8*)(ap + t * 32 + q * 8);
        } else {
            const float* ap = A + (size_t)rowc * HIDDIM;
            #pragma unroll
            for (int t = 0; t < 4; t++) {
                float4 u = *(const float4*)(ap + t * 32 + q * 8);
                float4 v = *(const float4*)(ap + t * 32 + q * 8 + 4);
                half8 h;
                h[0] = (_Float16)u.x; h[1] = (_Float16)u.y;
                h[2] = (_Float16)u.z; h[3] = (_Float16)u.w;
                h[4] = (_Float16)v.x; h[5] = (_Float16)v.y;
                h[6] = (_Float16)v.z; h[7] = (_Float16)v.w;
                a[t] = h;
            }
        }
        floatx4 acc[8];
        #pragma unroll
        for (int c = 0; c < 8; c++) acc[c] = (floatx4){0.f, 0.f, 0.f, 0.f};
        #pragma unroll
        for (int t = 0; t < 4; t++)
            #pragma unroll
            for (int c = 0; c < 8; c++)
                acc[c] = __builtin_amdgcn_mfma_f32_16x16x32_f16(a[t], bfrag[c][t], acc[c], 0, 0, 0);
        #pragma unroll
        for (int c = 0; c < 8; c++)
            #pragma unroll
            for (int r = 0; r < 4; r++) {
                int grow = rb + q * 4 + r;
                if (grow < M)
                    C16[(size_t)grow * HIDDIM + c * 16 + m] = __float2half(acc[c][r]);
            }
    }
}

// ---------------- attention logits (from fp16 h) ----------------

__global__ __launch_bounds__(256) void attn_k(const __half* __restrict__ h16,
                                              const float* __restrict__ att_src,
                                              const float* __restrict__ att_dst,
                                              float* __restrict__ aS, float* __restrict__ aD) {
    int lane = threadIdx.x & 63;
    int n = blockIdx.x * 4 + (threadIdx.x >> 6);
    if (n >= NNODES) return;
    int c2 = lane * 2;
    float2 hv = __half22float2(*(const __half2*)(h16 + (size_t)n * HIDDIM + c2));
    float ps = hv.x * att_src[c2] + hv.y * att_src[c2 + 1];
    float pd = hv.x * att_dst[c2] + hv.y * att_dst[c2 + 1];
    #pragma unroll
    for (int m = 1; m < 16; m <<= 1) {
        ps += __shfl_xor(ps, m);
        pd += __shfl_xor(pd, m);
    }
    if ((lane & 15) == 0) {
        aS[n * NHEAD + (lane >> 4)] = ps;
        aD[n * NHEAD + (lane >> 4)] = pd;
    }
}

// ---------------- aggregate: one 16-lane group per node ----------------
// 4 nodes per wave, 16 nodes per block. Each lane owns 8 channels exclusively:
// NO cross-lane reduction (wsum replicates within the group). Inner loop
// software-pipelined 2-deep (prefetch next edge's aS + h16 row).

template <bool HALF_OUT>
__global__ __launch_bounds__(256) void agg_k(const __half* __restrict__ h16,
                                             const int* __restrict__ offs,
                                             const int* __restrict__ deg,
                                             const int* __restrict__ srcs,
                                             const float* __restrict__ aS,
                                             const float* __restrict__ aD,
                                             const float* __restrict__ bias,
                                             void* __restrict__ outv) {
    int tid = threadIdx.x;
    int lane = tid & 63;
    int grp = lane >> 4;      // node group within wave (0..3)
    int cg = lane & 15;       // channel group within node
    int c8 = cg * 8;
    int head = cg >> 2;
    int n = blockIdx.x * 16 + (tid >> 6) * 4 + grp;
    bool nvalid = n < NNODES;
    int nn = nvalid ? n : NNODES - 1;
    int start = offs[nn];
    int cnt = deg[nn] + 1;
    float ad = aD[nn * NHEAD + head];
    half2t acc[4];
    #pragma unroll
    for (int i = 0; i < 4; i++) acc[i] = (half2t){(_Float16)0.f, (_Float16)0.f};
    float wsum = 0.f;
    const int base = grp * 16;

    for (int chunk = 0; chunk < cnt; chunk += 16) {
        int idx = chunk + cg;
        int lim = min(16, cnt - chunk);
        int sv = srcs[start + (idx < cnt ? idx : cnt - 1)];  // 16 edges prefetched/group
        int s_cur = __shfl(sv, base);
        float as_cur = aS[s_cur * NHEAD + head];
        half8 hv_cur = *(const half8*)(h16 + (size_t)s_cur * HIDDIM + c8);
        for (int j = 0; j < lim; j++) {
            int jn = (j + 1 < lim) ? j + 1 : j;
            int s_nxt = __shfl(sv, base + jn);
            float as_nxt = aS[s_nxt * NHEAD + head];
            half8 hv_nxt = *(const half8*)(h16 + (size_t)s_nxt * HIDDIM + c8);
            float e = as_cur + ad;
            e = (e > 0.f) ? e : 0.2f * e;
            float w = __expf(e);
            wsum += w;
            _Float16 wh = (_Float16)w;
            half2t w2 = (half2t){wh, wh};
            #pragma unroll
            for (int i = 0; i < 4; i++) {
                half2t hp = (half2t){hv_cur[2 * i], hv_cur[2 * i + 1]};
                acc[i] += w2 * hp;
            }
            as_cur = as_nxt;
            hv_cur = hv_nxt;
        }
    }

    if (nvalid) {
        float inv = 1.f / (wsum + 1e-16f);
        float v[8];
        #pragma unroll
        for (int i = 0; i < 4; i++) {
            float o0 = (float)acc[i][0] * inv + bias[c8 + 2 * i];
            float o1 = (float)acc[i][1] * inv + bias[c8 + 2 * i + 1];
            v[2 * i] = o0 > 0.f ? o0 : 0.f;
            v[2 * i + 1] = o1 > 0.f ? o1 : 0.f;
        }
        if constexpr (HALF_OUT) {
            union { uint4 u; __half2 h2[4]; } pk;
            #pragma unroll
            for (int i = 0; i < 4; i++) pk.h2[i] = __floats2half2_rn(v[2 * i], v[2 * i + 1]);
            *(uint4*)((__half*)outv + (size_t)n * HIDDIM + c8) = pk.u;
        } else {
            float* out = (float*)outv;
            *(float4*)(out + (size_t)n * HIDDIM + c8) = make_float4(v[0], v[1], v[2], v[3]);
            *(float4*)(out + (size_t)n * HIDDIM + c8 + 4) = make_float4(v[4], v[5], v[6], v[7]);
        }
    }
}

// ---------------- launch ----------------

extern "C" void kernel_launch(void* const* d_in, const int* in_sizes, int n_in,
                              void* d_out, int out_size, void* d_ws, size_t ws_size,
                              hipStream_t stream) {
    (void)in_sizes; (void)n_in; (void)out_size; (void)ws_size;
    const float* x = (const float*)d_in[0];

    char* ws = (char*)d_ws;
    size_t off = 0;
    auto alloc = [&](size_t bytes) -> void* {
        void* p = ws + off;
        off += (bytes + 255) & ~(size_t)255;
        return p;
    };
    __half* xh    = (__half*)alloc((size_t)NNODES * HIDDIM * 2);  // fp16 layer in/out
    __half* h16   = (__half*)alloc((size_t)NNODES * HIDDIM * 2);  // fp16 h
    float* aS     = (float*)alloc((size_t)NNODES * NHEAD * 4);
    float* aD     = (float*)alloc((size_t)NNODES * NHEAD * 4);
    int* deg      = (int*)alloc((size_t)NNODES * 4);
    int* offsArr  = (int*)alloc((size_t)NNODES * 4);
    int* rankArr  = (int*)alloc((size_t)NEDGES * 4);
    int* srcs     = (int*)alloc((size_t)(NEDGES + NNODES) * 4);
    int* blkSums  = (int*)alloc(128 * 4);

    const int nScan = (NNODES + 1023) / 1024;  // 98
    const int nScatBlk = ((NEDGES + NNODES + 255) / 256) * 8;
    for (int l = 0; l < 3; l++) {
        const int* ei      = (const int*)d_in[1 + 5 * l];
        const float* Wm    = (const float*)d_in[2 + 5 * l];
        const float* attS  = (const float*)d_in[3 + 5 * l];
        const float* attD  = (const float*)d_in[4 + 5 * l];
        const float* biasv = (const float*)d_in[5 + 5 * l];
        const int* srcRow = ei;
        const int* dstRow = ei + NEDGES;

        hipMemsetAsync(deg, 0, (size_t)NNODES * 4, stream);
        hipLaunchKernelGGL(hist_k, dim3((NEDGES + 255) / 256), dim3(256), 0, stream,
                           dstRow, deg, rankArr);
        hipLaunchKernelGGL(scan1_k, dim3(nScan), dim3(1024), 0, stream, deg, offsArr, blkSums);
        hipLaunchKernelGGL(scan2_k, dim3(1), dim3(128), 0, stream, blkSums, nScan);
        hipLaunchKernelGGL(scan3_k, dim3(nScan), dim3(1024), 0, stream, offsArr, blkSums);
        hipLaunchKernelGGL(scatter_k, dim3(nScatBlk), dim3(256), 0, stream,
                           srcRow, dstRow, rankArr, offsArr, deg, srcs);
        if (l == 0) {
            hipLaunchKernelGGL((gemm_mfma_k<float>), dim3((NNODES + 255) / 256), dim3(256), 0,
                               stream, x, Wm, h16, NNODES);
        } else {
            hipLaunchKernelGGL((gemm_mfma_k<__half>), dim3((NNODES + 255) / 256), dim3(256), 0,
                               stream, xh, Wm, h16, NNODES);
        }
        hipLaunchKernelGGL(attn_k, dim3((NNODES + 3) / 4), dim3(256), 0, stream,
                           h16, attS, attD, aS, aD);
        if (l == 2) {
            hipLaunchKernelGGL((agg_k<false>), dim3((NNODES + 15) / 16), dim3(256), 0, stream,
                               h16, offsArr, deg, srcs, aS, aD, biasv, d_out);
        } else {
            hipLaunchKernelGGL((agg_k<true>), dim3((NNODES + 15) / 16), dim3(256), 0, stream,
                               h16, offsArr, deg, srcs, aS, aD, biasv, (void*)xh);
        }
    }
}

// Round 8
// 485.116 us; speedup vs baseline: 1.8541x; 1.1146x over previous
//
#include <hip/hip_runtime.h>
#include <hip/hip_bf16.h>
#include <hip/hip_fp16.h>
#include <type_traits>

#define NNODES 100000
#define NEDGES 800000
#define HIDDIM 128
#define NHEAD 4
#define NSCAN 98   // (NNODES+1023)/1024

typedef _Float16 half8 __attribute__((ext_vector_type(8)));
typedef _Float16 half2t __attribute__((ext_vector_type(2)));
typedef float floatx4 __attribute__((ext_vector_type(4)));

// ---------------- CSR build (fused across 3 layers via blockIdx.y) ----------------

__global__ void hist_k(const int* __restrict__ e0, const int* __restrict__ e1,
                       const int* __restrict__ e2, int* __restrict__ deg,
                       int* __restrict__ rank) {
    int l = blockIdx.y;
    const int* ei = (l == 0) ? e0 : (l == 1) ? e1 : e2;
    const int* dst = ei + NEDGES;
    int e = blockIdx.x * 256 + threadIdx.x;
    if (e < NEDGES)
        rank[(size_t)l * NEDGES + e] = atomicAdd(&deg[l * NNODES + dst[e]], 1);
}

// block scan via wave shuffles
__global__ void scan1_k(const int* __restrict__ deg, int* __restrict__ offs,
                        int* __restrict__ blkSums) {
    __shared__ int wsums[16];
    int l = blockIdx.y;
    const int* degL = deg + l * NNODES;
    int* offsL = offs + l * NNODES;
    int t = threadIdx.x;
    int lane = t & 63, wv = t >> 6;
    int i = blockIdx.x * 1024 + t;
    int v = (i < NNODES) ? (degL[i] + 1) : 0;  // +1: self-loop slot
    int x = v;
    #pragma unroll
    for (int off = 1; off < 64; off <<= 1) {
        int u = __shfl_up(x, off);
        if (lane >= off) x += u;
    }
    if (lane == 63) wsums[wv] = x;
    __syncthreads();
    if (t < 16) {
        int y = wsums[t];
        #pragma unroll
        for (int off = 1; off < 16; off <<= 1) {
            int u = __shfl_up(y, off);
            if (t >= off) y += u;
        }
        wsums[t] = y;
    }
    __syncthreads();
    int pre = (wv > 0) ? wsums[wv - 1] : 0;
    if (i < NNODES) offsL[i] = pre + x - v;  // block-local exclusive
    if (t == 1023) blkSums[l * 128 + blockIdx.x] = wsums[15];
}

__global__ void scan2_k(int* __restrict__ blkSums) {
    __shared__ int sd[128];
    int* bs = blkSums + blockIdx.x * 128;
    int t = threadIdx.x;
    int v = (t < NSCAN) ? bs[t] : 0;
    sd[t] = v;
    __syncthreads();
    for (int off = 1; off < 128; off <<= 1) {
        int tv = (t >= off) ? sd[t - off] : 0;
        __syncthreads();
        sd[t] += tv;
        __syncthreads();
    }
    if (t < NSCAN) bs[t] = sd[t] - v;  // exclusive block offsets
}

// XCD-range-partitioned scatter, fused across layers; blkSums folded in.
__global__ __launch_bounds__(256) void scatter_k(const int* __restrict__ e0,
                                                 const int* __restrict__ e1,
                                                 const int* __restrict__ e2,
                                                 const int* __restrict__ rank,
                                                 const int* __restrict__ offs,
                                                 const int* __restrict__ deg,
                                                 const int* __restrict__ blkSums,
                                                 int* __restrict__ srcs) {
    int l = blockIdx.y;
    const int* ei = (l == 0) ? e0 : (l == 1) ? e1 : e2;
    const int* srcRow = ei;
    const int* dstRow = ei + NEDGES;
    const int* rankL = rank + (size_t)l * NEDGES;
    const int* offsL = offs + l * NNODES;
    const int* degL = deg + l * NNODES;
    const int* bsL = blkSums + l * 128;
    int* srcsL = srcs + (size_t)l * (NEDGES + NNODES);

    int group = blockIdx.x & 7;
    int t = (blockIdx.x >> 3) * 256 + threadIdx.x;
    int lo = group * (NNODES / 8);
    int hi = lo + (NNODES / 8);
    if (t < NEDGES) {
        int d = dstRow[t];
        if (d >= lo && d < hi)
            srcsL[offsL[d] + bsL[d >> 10] + rankL[t]] = srcRow[t];
    } else if (t < NEDGES + NNODES) {
        int n = t - NEDGES;
        if (n >= lo && n < hi)
            srcsL[offsL[n] + bsL[n >> 10] + degL[n]] = n;  // self-loop in last slot
    }
}

// ---------------- GEMM + attention logits via extended-N MFMA ----------------
// h16[M,128] = fp16(A @ B); aSD[M,8] = logits (col j = head*2 + {0:src,1:dst}).
// Since (x@W)·att == x·(W@att), the appended columns 128..135 hold
// Wa[k][j] = sum_{c=0..31} W[k][h*32+c]*att_{s}[h][c]  (h=j>>1, s=j&1),
// computed in fp32 during staging. Columns 136..143 are zero.

template <typename AT>
__global__ __launch_bounds__(256, 2) void gemm_mfma_k(const AT* __restrict__ A,
                                                      const float* __restrict__ B,
                                                      const float* __restrict__ attS,
                                                      const float* __restrict__ attD,
                                                      __half* __restrict__ C16,
                                                      float* __restrict__ aSD, int M) {
    __shared__ __half Bt[144 * 136];  // Bt[n][k]; rows 128..135 Wa cols, 136..143 zero
    const int tid = threadIdx.x;
    {   // stage B transposed as fp16 (rows 0..127)
        int kk = (tid & 63) * 2;
        int g = tid >> 6;
        #pragma unroll
        for (int jn = 0; jn < 8; jn++) {
            int n0 = g * 4 + jn * 16;
            float4 r0 = *(const float4*)(B + (size_t)kk * 128 + n0);
            float4 r1 = *(const float4*)(B + (size_t)(kk + 1) * 128 + n0);
            float f0[4] = {r0.x, r0.y, r0.z, r0.w};
            float f1[4] = {r1.x, r1.y, r1.z, r1.w};
            #pragma unroll
            for (int i = 0; i < 4; i++)
                *(__half2*)(&Bt[(n0 + i) * 136 + kk]) = __floats2half2_rn(f0[i], f1[i]);
        }
    }
    // stage Wa columns (rows 128..135) in fp32, + zeros (rows 136..143)
    if (tid < 128) {
        int k = tid;
        const float* Brow = B + (size_t)k * 128;
        #pragma unroll
        for (int h = 0; h < NHEAD; h++) {
            float s0 = 0.f, s1 = 0.f;
            #pragma unroll 8
            for (int c = 0; c < 32; c++) {
                float b = Brow[h * 32 + c];
                s0 += b * attS[h * 32 + c];
                s1 += b * attD[h * 32 + c];
            }
            Bt[(128 + h * 2 + 0) * 136 + k] = (_Float16)s0;
            Bt[(128 + h * 2 + 1) * 136 + k] = (_Float16)s1;
        }
    } else {
        int k = tid - 128;
        #pragma unroll
        for (int j = 8; j < 16; j++) Bt[(128 + j) * 136 + k] = (_Float16)0.f;
    }
    __syncthreads();

    const int lane = tid & 63;
    const int wave = tid >> 6;
    const int m = lane & 15;
    const int q = lane >> 4;

    half8 bfrag[9][4];
    #pragma unroll
    for (int c = 0; c < 9; c++)
        #pragma unroll
        for (int t = 0; t < 4; t++)
            bfrag[c][t] = *(const half8*)(&Bt[(c * 16 + m) * 136 + t * 32 + q * 8]);

    for (int iter = 0; iter < 4; iter++) {
        int rb = blockIdx.x * 256 + iter * 64 + wave * 16;  // wave-uniform
        if (rb >= M) break;
        int row = rb + m;
        int rowc = row < M ? row : M - 1;
        half8 a[4];
        if constexpr (std::is_same<AT, __half>::value) {
            const __half* ap = A + (size_t)rowc * HIDDIM;
            #pragma unroll
            for (int t = 0; t < 4; t++)
                a[t] = *(const half8*)(ap + t * 32 + q * 8);
        } else {
            const float* ap = A + (size_t)rowc * HIDDIM;
            #pragma unroll
            for (int t = 0; t < 4; t++) {
                float4 u = *(const float4*)(ap + t * 32 + q * 8);
                float4 v = *(const float4*)(ap + t * 32 + q * 8 + 4);
                half8 h;
                h[0] = (_Float16)u.x; h[1] = (_Float16)u.y;
                h[2] = (_Float16)u.z; h[3] = (_Float16)u.w;
                h[4] = (_Float16)v.x; h[5] = (_Float16)v.y;
                h[6] = (_Float16)v.z; h[7] = (_Float16)v.w;
                a[t] = h;
            }
        }
        floatx4 acc[9];
        #pragma unroll
        for (int c = 0; c < 9; c++) acc[c] = (floatx4){0.f, 0.f, 0.f, 0.f};
        #pragma unroll
        for (int t = 0; t < 4; t++)
            #pragma unroll
            for (int c = 0; c < 9; c++)
                acc[c] = __builtin_amdgcn_mfma_f32_16x16x32_f16(a[t], bfrag[c][t], acc[c], 0, 0, 0);
        #pragma unroll
        for (int c = 0; c < 8; c++)
            #pragma unroll
            for (int r = 0; r < 4; r++) {
                int grow = rb + q * 4 + r;
                if (grow < M)
                    C16[(size_t)grow * HIDDIM + c * 16 + m] = __float2half(acc[c][r]);
            }
        if (m < 8) {
            #pragma unroll
            for (int r = 0; r < 4; r++) {
                int grow = rb + q * 4 + r;
                if (grow < M) aSD[(size_t)grow * 8 + m] = acc[8][r];
            }
        }
    }
}

// ---------------- aggregate: one 16-lane group per node, 2-deep pipeline ----------------

template <bool HALF_OUT>
__global__ __launch_bounds__(256) void agg_k(const __half* __restrict__ h16,
                                             const int* __restrict__ offs,
                                             const int* __restrict__ blkSums,
                                             const int* __restrict__ deg,
                                             const int* __restrict__ srcs,
                                             const float* __restrict__ aSD,
                                             const float* __restrict__ bias,
                                             void* __restrict__ outv) {
    int tid = threadIdx.x;
    int lane = tid & 63;
    int grp = lane >> 4;      // node group within wave (0..3)
    int cg = lane & 15;       // channel group within node
    int c8 = cg * 8;
    int h2 = (cg >> 2) * 2;   // head*2
    int n = blockIdx.x * 16 + (tid >> 6) * 4 + grp;
    bool nvalid = n < NNODES;
    int nn = nvalid ? n : NNODES - 1;
    int start = offs[nn] + blkSums[nn >> 10];
    int cnt = deg[nn] + 1;
    float ad = aSD[(size_t)nn * 8 + h2 + 1];
    half2t acc0[4], acc1[4];
    #pragma unroll
    for (int i = 0; i < 4; i++) {
        acc0[i] = (half2t){(_Float16)0.f, (_Float16)0.f};
        acc1[i] = (half2t){(_Float16)0.f, (_Float16)0.f};
    }
    float wsum = 0.f;
    const int base = grp * 16;

    for (int chunk = 0; chunk < cnt; chunk += 16) {
        int idx = chunk + cg;
        int lim = min(16, cnt - chunk);
        int sv = srcs[start + (idx < cnt ? idx : cnt - 1)];  // clamped: always valid
        int s_a = __shfl(sv, base + 0);
        int s_b = __shfl(sv, base + 1);
        float as_a = aSD[(size_t)s_a * 8 + h2];
        float as_b = aSD[(size_t)s_b * 8 + h2];
        half8 hv_a = *(const half8*)(h16 + (size_t)s_a * HIDDIM + c8);
        half8 hv_b = *(const half8*)(h16 + (size_t)s_b * HIDDIM + c8);
        for (int j = 0; j < lim; j += 2) {
            int j2 = (j + 2 < 16) ? j + 2 : 15;
            int j3 = (j + 3 < 16) ? j + 3 : 15;
            int s_c = __shfl(sv, base + j2);
            int s_d = __shfl(sv, base + j3);
            float as_c = aSD[(size_t)s_c * 8 + h2];
            float as_d = aSD[(size_t)s_d * 8 + h2];
            half8 hv_c = *(const half8*)(h16 + (size_t)s_c * HIDDIM + c8);
            half8 hv_d = *(const half8*)(h16 + (size_t)s_d * HIDDIM + c8);

            float e0 = as_a + ad;
            e0 = (e0 > 0.f) ? e0 : 0.2f * e0;
            float w0 = __expf(e0);
            float e1 = as_b + ad;
            e1 = (e1 > 0.f) ? e1 : 0.2f * e1;
            float w1 = (j + 1 < lim) ? __expf(e1) : 0.f;
            wsum += w0 + w1;
            _Float16 w0h = (_Float16)w0, w1h = (_Float16)w1;
            half2t w02 = (half2t){w0h, w0h}, w12 = (half2t){w1h, w1h};
            #pragma unroll
            for (int i = 0; i < 4; i++) {
                acc0[i] += w02 * (half2t){hv_a[2 * i], hv_a[2 * i + 1]};
                acc1[i] += w12 * (half2t){hv_b[2 * i], hv_b[2 * i + 1]};
            }
            as_a = as_c; as_b = as_d;
            hv_a = hv_c; hv_b = hv_d;
        }
    }

    if (nvalid) {
        float inv = 1.f / (wsum + 1e-16f);
        float v[8];
        #pragma unroll
        for (int i = 0; i < 4; i++) {
            half2t s = acc0[i] + acc1[i];
            float o0 = (float)s[0] * inv + bias[c8 + 2 * i];
            float o1 = (float)s[1] * inv + bias[c8 + 2 * i + 1];
            v[2 * i] = o0 > 0.f ? o0 : 0.f;
            v[2 * i + 1] = o1 > 0.f ? o1 : 0.f;
        }
        if constexpr (HALF_OUT) {
            union { uint4 u; __half2 h2v[4]; } pk;
            #pragma unroll
            for (int i = 0; i < 4; i++) pk.h2v[i] = __floats2half2_rn(v[2 * i], v[2 * i + 1]);
            *(uint4*)((__half*)outv + (size_t)n * HIDDIM + c8) = pk.u;
        } else {
            float* out = (float*)outv;
            *(float4*)(out + (size_t)n * HIDDIM + c8) = make_float4(v[0], v[1], v[2], v[3]);
            *(float4*)(out + (size_t)n * HIDDIM + c8 + 4) = make_float4(v[4], v[5], v[6], v[7]);
        }
    }
}

// ---------------- launch ----------------

extern "C" void kernel_launch(void* const* d_in, const int* in_sizes, int n_in,
                              void* d_out, int out_size, void* d_ws, size_t ws_size,
                              hipStream_t stream) {
    (void)in_sizes; (void)n_in; (void)out_size; (void)ws_size;
    const float* x = (const float*)d_in[0];
    const int* e0 = (const int*)d_in[1];
    const int* e1 = (const int*)d_in[6];
    const int* e2 = (const int*)d_in[11];

    char* ws = (char*)d_ws;
    size_t off = 0;
    auto alloc = [&](size_t bytes) -> void* {
        void* p = ws + off;
        off += (bytes + 255) & ~(size_t)255;
        return p;
    };
    __half* xh    = (__half*)alloc((size_t)NNODES * HIDDIM * 2);
    __half* h16   = (__half*)alloc((size_t)NNODES * HIDDIM * 2);
    float* aSD    = (float*)alloc((size_t)NNODES * 8 * 4);
    int* deg      = (int*)alloc((size_t)3 * NNODES * 4);
    int* offsArr  = (int*)alloc((size_t)3 * NNODES * 4);
    int* rankArr  = (int*)alloc((size_t)3 * NEDGES * 4);
    int* srcs     = (int*)alloc((size_t)3 * (NEDGES + NNODES) * 4);
    int* blkSums  = (int*)alloc(3 * 128 * 4);

    const int nScatBlk = ((NEDGES + NNODES + 255) / 256) * 8;

    // fused CSR build for all 3 layers
    hipMemsetAsync(deg, 0, (size_t)3 * NNODES * 4, stream);
    hipLaunchKernelGGL(hist_k, dim3((NEDGES + 255) / 256, 3), dim3(256), 0, stream,
                       e0, e1, e2, deg, rankArr);
    hipLaunchKernelGGL(scan1_k, dim3(NSCAN, 3), dim3(1024), 0, stream,
                       deg, offsArr, blkSums);
    hipLaunchKernelGGL(scan2_k, dim3(3), dim3(128), 0, stream, blkSums);
    hipLaunchKernelGGL(scatter_k, dim3(nScatBlk, 3), dim3(256), 0, stream,
                       e0, e1, e2, rankArr, offsArr, deg, blkSums, srcs);

    for (int l = 0; l < 3; l++) {
        const float* Wm    = (const float*)d_in[2 + 5 * l];
        const float* attS  = (const float*)d_in[3 + 5 * l];
        const float* attD  = (const float*)d_in[4 + 5 * l];
        const float* biasv = (const float*)d_in[5 + 5 * l];
        const int* offsL = offsArr + l * NNODES;
        const int* degL  = deg + l * NNODES;
        const int* bsL   = blkSums + l * 128;
        const int* srcsL = srcs + (size_t)l * (NEDGES + NNODES);

        if (l == 0) {
            hipLaunchKernelGGL((gemm_mfma_k<float>), dim3((NNODES + 255) / 256), dim3(256), 0,
                               stream, x, Wm, attS, attD, h16, aSD, NNODES);
        } else {
            hipLaunchKernelGGL((gemm_mfma_k<__half>), dim3((NNODES + 255) / 256), dim3(256), 0,
                               stream, xh, Wm, attS, attD, h16, aSD, NNODES);
        }
        if (l == 2) {
            hipLaunchKernelGGL((agg_k<false>), dim3((NNODES + 15) / 16), dim3(256), 0, stream,
                               h16, offsL, bsL, degL, srcsL, aSD, biasv, d_out);
        } else {
            hipLaunchKernelGGL((agg_k<true>), dim3((NNODES + 15) / 16), dim3(256), 0, stream,
                               h16, offsL, bsL, degL, srcsL, aSD, biasv, (void*)xh);
        }
    }
}

// Round 9
// 414.085 us; speedup vs baseline: 2.1722x; 1.1715x over previous
//
#include <hip/hip_runtime.h>
#include <hip/hip_bf16.h>
#include <hip/hip_fp16.h>
#include <type_traits>

#define NNODES 100000
#define NEDGES 800000
#define HIDDIM 128
#define NHEAD 4

// bucket sort parameters
#define EPB 8192                 // edges per chunk-block
#define NBLK 98                  // ceil(NEDGES / EPB)
#define BSH 7                    // 128 nodes per bucket
#define NBUCK 782                // ceil(NNODES / 128); last bucket has 32 nodes

typedef _Float16 half8 __attribute__((ext_vector_type(8)));
typedef _Float16 half2t __attribute__((ext_vector_type(2)));
typedef float floatx4 __attribute__((ext_vector_type(4)));

// ---------------- CSR build via bucket counting-sort (no global atomics) ----------------

// Phase A: per-(chunk, bucket) histogram in LDS, non-atomic global write.
__global__ __launch_bounds__(256) void bucketA_k(const int* __restrict__ e0,
                                                 const int* __restrict__ e1,
                                                 const int* __restrict__ e2,
                                                 int* __restrict__ counts) {
    __shared__ int hist[NBUCK];
    int l = blockIdx.y;
    const int* dst = ((l == 0) ? e0 : (l == 1) ? e1 : e2) + NEDGES;
    int j = blockIdx.x;
    for (int t = threadIdx.x; t < NBUCK; t += 256) hist[t] = 0;
    __syncthreads();
    int base = j * EPB;
    int lim = min(EPB, NEDGES - base);
    for (int i = threadIdx.x; i < lim; i += 256)
        atomicAdd(&hist[dst[base + i] >> BSH], 1);
    __syncthreads();
    int* crow = counts + ((size_t)l * NBLK + j) * NBUCK;
    for (int t = threadIdx.x; t < NBUCK; t += 256) crow[t] = hist[t];
}

// Phase B1: per-bucket exclusive scan over the 98 chunk counts (in place) + bucket totals.
__global__ __launch_bounds__(128) void bucketB1_k(int* __restrict__ counts,
                                                  int* __restrict__ bucketTotal) {
    __shared__ int sd[128];
    int b = blockIdx.x, l = blockIdx.y;
    int t = threadIdx.x;
    int v = (t < NBLK) ? counts[((size_t)l * NBLK + t) * NBUCK + b] : 0;
    sd[t] = v;
    __syncthreads();
    for (int off = 1; off < 128; off <<= 1) {
        int u = (t >= off) ? sd[t - off] : 0;
        __syncthreads();
        sd[t] += u;
        __syncthreads();
    }
    if (t < NBLK) counts[((size_t)l * NBLK + t) * NBUCK + b] = sd[t] - v;  // exclusive
    if (t == 127) bucketTotal[l * NBUCK + b] = sd[127];
}

// Phase B2: per-layer exclusive scans over buckets: edgeBuf bases (raw totals)
// and CSR bases (totals + nodes-in-bucket for self-loop slots).
__global__ __launch_bounds__(1024) void bucketB2_k(const int* __restrict__ bucketTotal,
                                                   int* __restrict__ ebBase,
                                                   int* __restrict__ csrBase) {
    __shared__ int sd[1024];
    int l = blockIdx.x;
    int t = threadIdx.x;
    int tot = (t < NBUCK) ? bucketTotal[l * NBUCK + t] : 0;
    sd[t] = tot;
    __syncthreads();
    for (int off = 1; off < 1024; off <<= 1) {
        int u = (t >= off) ? sd[t - off] : 0;
        __syncthreads();
        sd[t] += u;
        __syncthreads();
    }
    if (t < NBUCK) ebBase[l * NBUCK + t] = sd[t] - tot;
    __syncthreads();
    int nb = (t == NBUCK - 1) ? (NNODES - (NBUCK - 1) * 128) : 128;
    int v2 = (t < NBUCK) ? (tot + nb) : 0;
    sd[t] = v2;
    __syncthreads();
    for (int off = 1; off < 1024; off <<= 1) {
        int u = (t >= off) ? sd[t - off] : 0;
        __syncthreads();
        sd[t] += u;
        __syncthreads();
    }
    if (t < NBUCK) csrBase[l * NBUCK + t] = sd[t] - v2;
}

// Phase C: scatter edges into bucket-grouped edgeBuf, packed (dstLocal<<17)|src.
// Cursors live in LDS (per-block disjoint sub-ranges; LDS atomics only).
__global__ __launch_bounds__(256) void bucketC_k(const int* __restrict__ e0,
                                                 const int* __restrict__ e1,
                                                 const int* __restrict__ e2,
                                                 const int* __restrict__ counts,
                                                 const int* __restrict__ ebBase,
                                                 int* __restrict__ edgeBuf) {
    __shared__ int cur[NBUCK];
    int l = blockIdx.y;
    const int* ei = (l == 0) ? e0 : (l == 1) ? e1 : e2;
    const int* src = ei;
    const int* dst = ei + NEDGES;
    int j = blockIdx.x;
    const int* bs = counts + ((size_t)l * NBLK + j) * NBUCK;
    const int* eb = ebBase + l * NBUCK;
    for (int t = threadIdx.x; t < NBUCK; t += 256) cur[t] = eb[t] + bs[t];
    __syncthreads();
    int base = j * EPB;
    int lim = min(EPB, NEDGES - base);
    int* ebuf = edgeBuf + (size_t)l * NEDGES;
    for (int i = threadIdx.x; i < lim; i += 256) {
        int d = dst[base + i];
        int s = src[base + i];
        int pos = atomicAdd(&cur[d >> BSH], 1);
        ebuf[pos] = ((d & 127) << 17) | s;
    }
}

// Phase D: one block per bucket: per-node counts, wave-shuffle scan, write
// offs/deg, scatter srcs + self-loops. Single-block ownership of the region.
__global__ __launch_bounds__(256) void bucketD_k(const int* __restrict__ edgeBuf,
                                                 const int* __restrict__ bucketTotal,
                                                 const int* __restrict__ ebBase,
                                                 const int* __restrict__ csrBase,
                                                 int* __restrict__ offs,
                                                 int* __restrict__ deg,
                                                 int* __restrict__ srcs) {
    __shared__ int cnt[128];
    __shared__ int offl[128];
    __shared__ int cur[128];
    int b = blockIdx.x, l = blockIdx.y;
    int t = threadIdx.x;
    int nb = (b == NBUCK - 1) ? (NNODES - (NBUCK - 1) * 128) : 128;
    int eb0 = ebBase[l * NBUCK + b];
    int ecnt = bucketTotal[l * NBUCK + b];
    int csr0 = csrBase[l * NBUCK + b];
    const int* ebuf = edgeBuf + (size_t)l * NEDGES;
    int* srcsL = srcs + (size_t)l * (NEDGES + NNODES);
    if (t < 128) cnt[t] = 0;
    __syncthreads();
    for (int i = t; i < ecnt; i += 256)
        atomicAdd(&cnt[ebuf[eb0 + i] >> 17], 1);
    __syncthreads();
    if (t < 128) {
        int lane = t & 63;
        int x = cnt[t] + 1;  // +1 self-loop slot (pad nodes harmless: trail real nodes)
        #pragma unroll
        for (int o = 1; o < 64; o <<= 1) {
            int u = __shfl_up(x, o);
            if (lane >= o) x += u;
        }
        offl[t] = x;  // inclusive within wave
    }
    __syncthreads();
    if (t < 128) {
        int c = cnt[t];
        int incl = offl[t] + ((t >= 64) ? offl[63] : 0);
        int o = csr0 + incl - (c + 1);  // exclusive
        cur[t] = o;
        if (t < nb) {
            int node = b * 128 + t;
            offs[l * NNODES + node] = o;
            deg[l * NNODES + node] = c;
            srcsL[o + c] = node;  // self-loop in last slot
        }
    }
    __syncthreads();
    for (int i = t; i < ecnt; i += 256) {
        int w = ebuf[eb0 + i];
        int pos = atomicAdd(&cur[w >> 17], 1);
        srcsL[pos] = w & 0x1FFFF;
    }
}

// ---------------- GEMM + attention logits via extended-N MFMA ----------------
// h16[M,128] = fp16(A @ B); aSD[M,8] = logits (col j = head*2 + {0:src,1:dst}).
// (x@W)·att == x·(W@att): appended columns 128..135 hold Wa = W @ att_masked.

template <typename AT>
__global__ __launch_bounds__(256, 2) void gemm_mfma_k(const AT* __restrict__ A,
                                                      const float* __restrict__ B,
                                                      const float* __restrict__ attS,
                                                      const float* __restrict__ attD,
                                                      __half* __restrict__ C16,
                                                      float* __restrict__ aSD, int M) {
    __shared__ __half Bt[144 * 136];  // Bt[n][k]; rows 128..135 Wa cols, 136..143 zero
    const int tid = threadIdx.x;
    {   // stage B transposed as fp16 (rows 0..127)
        int kk = (tid & 63) * 2;
        int g = tid >> 6;
        #pragma unroll
        for (int jn = 0; jn < 8; jn++) {
            int n0 = g * 4 + jn * 16;
            float4 r0 = *(const float4*)(B + (size_t)kk * 128 + n0);
            float4 r1 = *(const float4*)(B + (size_t)(kk + 1) * 128 + n0);
            float f0[4] = {r0.x, r0.y, r0.z, r0.w};
            float f1[4] = {r1.x, r1.y, r1.z, r1.w};
            #pragma unroll
            for (int i = 0; i < 4; i++)
                *(__half2*)(&Bt[(n0 + i) * 136 + kk]) = __floats2half2_rn(f0[i], f1[i]);
        }
    }
    if (tid < 128) {  // Wa columns (rows 128..135), fp32 accumulate
        int k = tid;
        const float* Brow = B + (size_t)k * 128;
        #pragma unroll
        for (int h = 0; h < NHEAD; h++) {
            float s0 = 0.f, s1 = 0.f;
            #pragma unroll 8
            for (int c = 0; c < 32; c++) {
                float bb = Brow[h * 32 + c];
                s0 += bb * attS[h * 32 + c];
                s1 += bb * attD[h * 32 + c];
            }
            Bt[(128 + h * 2 + 0) * 136 + k] = (_Float16)s0;
            Bt[(128 + h * 2 + 1) * 136 + k] = (_Float16)s1;
        }
    } else {
        int k = tid - 128;
        #pragma unroll
        for (int j = 8; j < 16; j++) Bt[(128 + j) * 136 + k] = (_Float16)0.f;
    }
    __syncthreads();

    const int lane = tid & 63;
    const int wave = tid >> 6;
    const int m = lane & 15;
    const int q = lane >> 4;

    half8 bfrag[9][4];
    #pragma unroll
    for (int c = 0; c < 9; c++)
        #pragma unroll
        for (int t = 0; t < 4; t++)
            bfrag[c][t] = *(const half8*)(&Bt[(c * 16 + m) * 136 + t * 32 + q * 8]);

    for (int iter = 0; iter < 4; iter++) {
        int rb = blockIdx.x * 256 + iter * 64 + wave * 16;  // wave-uniform
        if (rb >= M) break;
        int row = rb + m;
        int rowc = row < M ? row : M - 1;
        half8 a[4];
        if constexpr (std::is_same<AT, __half>::value) {
            const __half* ap = A + (size_t)rowc * HIDDIM;
            #pragma unroll
            for (int t = 0; t < 4; t++)
                a[t] = *(const half8*)(ap + t * 32 + q * 8);
        } else {
            const float* ap = A + (size_t)rowc * HIDDIM;
            #pragma unroll
            for (int t = 0; t < 4; t++) {
                float4 u = *(const float4*)(ap + t * 32 + q * 8);
                float4 v = *(const float4*)(ap + t * 32 + q * 8 + 4);
                half8 h;
                h[0] = (_Float16)u.x; h[1] = (_Float16)u.y;
                h[2] = (_Float16)u.z; h[3] = (_Float16)u.w;
                h[4] = (_Float16)v.x; h[5] = (_Float16)v.y;
                h[6] = (_Float16)v.z; h[7] = (_Float16)v.w;
                a[t] = h;
            }
        }
        floatx4 acc[9];
        #pragma unroll
        for (int c = 0; c < 9; c++) acc[c] = (floatx4){0.f, 0.f, 0.f, 0.f};
        #pragma unroll
        for (int t = 0; t < 4; t++)
            #pragma unroll
            for (int c = 0; c < 9; c++)
                acc[c] = __builtin_amdgcn_mfma_f32_16x16x32_f16(a[t], bfrag[c][t], acc[c], 0, 0, 0);
        #pragma unroll
        for (int c = 0; c < 8; c++)
            #pragma unroll
            for (int r = 0; r < 4; r++) {
                int grow = rb + q * 4 + r;
                if (grow < M)
                    C16[(size_t)grow * HIDDIM + c * 16 + m] = __float2half(acc[c][r]);
            }
        if (m < 8) {
            #pragma unroll
            for (int r = 0; r < 4; r++) {
                int grow = rb + q * 4 + r;
                if (grow < M) aSD[(size_t)grow * 8 + m] = acc[8][r];
            }
        }
    }
}

// ---------------- aggregate: one 16-lane group per node, 2-deep pipeline ----------------

template <bool HALF_OUT>
__global__ __launch_bounds__(256) void agg_k(const __half* __restrict__ h16,
                                             const int* __restrict__ offs,
                                             const int* __restrict__ deg,
                                             const int* __restrict__ srcs,
                                             const float* __restrict__ aSD,
                                             const float* __restrict__ bias,
                                             void* __restrict__ outv) {
    int tid = threadIdx.x;
    int lane = tid & 63;
    int grp = lane >> 4;      // node group within wave (0..3)
    int cg = lane & 15;       // channel group within node
    int c8 = cg * 8;
    int h2 = (cg >> 2) * 2;   // head*2
    int n = blockIdx.x * 16 + (tid >> 6) * 4 + grp;
    bool nvalid = n < NNODES;
    int nn = nvalid ? n : NNODES - 1;
    int start = offs[nn];
    int cnt = deg[nn] + 1;
    float ad = aSD[(size_t)nn * 8 + h2 + 1];
    half2t acc0[4], acc1[4];
    #pragma unroll
    for (int i = 0; i < 4; i++) {
        acc0[i] = (half2t){(_Float16)0.f, (_Float16)0.f};
        acc1[i] = (half2t){(_Float16)0.f, (_Float16)0.f};
    }
    float wsum = 0.f;
    const int base = grp * 16;

    for (int chunk = 0; chunk < cnt; chunk += 16) {
        int idx = chunk + cg;
        int lim = min(16, cnt - chunk);
        int sv = srcs[start + (idx < cnt ? idx : cnt - 1)];  // clamped: always valid
        int s_a = __shfl(sv, base + 0);
        int s_b = __shfl(sv, base + 1);
        float as_a = aSD[(size_t)s_a * 8 + h2];
        float as_b = aSD[(size_t)s_b * 8 + h2];
        half8 hv_a = *(const half8*)(h16 + (size_t)s_a * HIDDIM + c8);
        half8 hv_b = *(const half8*)(h16 + (size_t)s_b * HIDDIM + c8);
        for (int j = 0; j < lim; j += 2) {
            int j2 = (j + 2 < 16) ? j + 2 : 15;
            int j3 = (j + 3 < 16) ? j + 3 : 15;
            int s_c = __shfl(sv, base + j2);
            int s_d = __shfl(sv, base + j3);
            float as_c = aSD[(size_t)s_c * 8 + h2];
            float as_d = aSD[(size_t)s_d * 8 + h2];
            half8 hv_c = *(const half8*)(h16 + (size_t)s_c * HIDDIM + c8);
            half8 hv_d = *(const half8*)(h16 + (size_t)s_d * HIDDIM + c8);

            float e0 = as_a + ad;
            e0 = (e0 > 0.f) ? e0 : 0.2f * e0;
            float w0 = __expf(e0);
            float e1 = as_b + ad;
            e1 = (e1 > 0.f) ? e1 : 0.2f * e1;
            float w1 = (j + 1 < lim) ? __expf(e1) : 0.f;
            wsum += w0 + w1;
            _Float16 w0h = (_Float16)w0, w1h = (_Float16)w1;
            half2t w02 = (half2t){w0h, w0h}, w12 = (half2t){w1h, w1h};
            #pragma unroll
            for (int i = 0; i < 4; i++) {
                acc0[i] += w02 * (half2t){hv_a[2 * i], hv_a[2 * i + 1]};
                acc1[i] += w12 * (half2t){hv_b[2 * i], hv_b[2 * i + 1]};
            }
            as_a = as_c; as_b = as_d;
            hv_a = hv_c; hv_b = hv_d;
        }
    }

    if (nvalid) {
        float inv = 1.f / (wsum + 1e-16f);
        float v[8];
        #pragma unroll
        for (int i = 0; i < 4; i++) {
            half2t s = acc0[i] + acc1[i];
            float o0 = (float)s[0] * inv + bias[c8 + 2 * i];
            float o1 = (float)s[1] * inv + bias[c8 + 2 * i + 1];
            v[2 * i] = o0 > 0.f ? o0 : 0.f;
            v[2 * i + 1] = o1 > 0.f ? o1 : 0.f;
        }
        if constexpr (HALF_OUT) {
            union { uint4 u; __half2 h2v[4]; } pk;
            #pragma unroll
            for (int i = 0; i < 4; i++) pk.h2v[i] = __floats2half2_rn(v[2 * i], v[2 * i + 1]);
            *(uint4*)((__half*)outv + (size_t)n * HIDDIM + c8) = pk.u;
        } else {
            float* out = (float*)outv;
            *(float4*)(out + (size_t)n * HIDDIM + c8) = make_float4(v[0], v[1], v[2], v[3]);
            *(float4*)(out + (size_t)n * HIDDIM + c8 + 4) = make_float4(v[4], v[5], v[6], v[7]);
        }
    }
}

// ---------------- launch ----------------

extern "C" void kernel_launch(void* const* d_in, const int* in_sizes, int n_in,
                              void* d_out, int out_size, void* d_ws, size_t ws_size,
                              hipStream_t stream) {
    (void)in_sizes; (void)n_in; (void)out_size; (void)ws_size;
    const float* x = (const float*)d_in[0];
    const int* e0 = (const int*)d_in[1];
    const int* e1 = (const int*)d_in[6];
    const int* e2 = (const int*)d_in[11];

    char* ws = (char*)d_ws;
    size_t off = 0;
    auto alloc = [&](size_t bytes) -> void* {
        void* p = ws + off;
        off += (bytes + 255) & ~(size_t)255;
        return p;
    };
    __half* xh      = (__half*)alloc((size_t)NNODES * HIDDIM * 2);
    __half* h16     = (__half*)alloc((size_t)NNODES * HIDDIM * 2);
    float* aSD      = (float*)alloc((size_t)NNODES * 8 * 4);
    int* deg        = (int*)alloc((size_t)3 * NNODES * 4);
    int* offsArr    = (int*)alloc((size_t)3 * NNODES * 4);
    int* srcs       = (int*)alloc((size_t)3 * (NEDGES + NNODES) * 4);
    int* counts     = (int*)alloc((size_t)3 * NBLK * NBUCK * 4);
    int* bucketTot  = (int*)alloc((size_t)3 * NBUCK * 4);
    int* ebBase     = (int*)alloc((size_t)3 * NBUCK * 4);
    int* csrBase    = (int*)alloc((size_t)3 * NBUCK * 4);
    int* edgeBuf    = (int*)alloc((size_t)3 * NEDGES * 4);

    // CSR build for all 3 layers — no global atomics
    hipLaunchKernelGGL(bucketA_k, dim3(NBLK, 3), dim3(256), 0, stream, e0, e1, e2, counts);
    hipLaunchKernelGGL(bucketB1_k, dim3(NBUCK, 3), dim3(128), 0, stream, counts, bucketTot);
    hipLaunchKernelGGL(bucketB2_k, dim3(3), dim3(1024), 0, stream, bucketTot, ebBase, csrBase);
    hipLaunchKernelGGL(bucketC_k, dim3(NBLK, 3), dim3(256), 0, stream,
                       e0, e1, e2, counts, ebBase, edgeBuf);
    hipLaunchKernelGGL(bucketD_k, dim3(NBUCK, 3), dim3(256), 0, stream,
                       edgeBuf, bucketTot, ebBase, csrBase, offsArr, deg, srcs);

    for (int l = 0; l < 3; l++) {
        const float* Wm    = (const float*)d_in[2 + 5 * l];
        const float* attS  = (const float*)d_in[3 + 5 * l];
        const float* attD  = (const float*)d_in[4 + 5 * l];
        const float* biasv = (const float*)d_in[5 + 5 * l];
        const int* offsL = offsArr + l * NNODES;
        const int* degL  = deg + l * NNODES;
        const int* srcsL = srcs + (size_t)l * (NEDGES + NNODES);

        if (l == 0) {
            hipLaunchKernelGGL((gemm_mfma_k<float>), dim3((NNODES + 255) / 256), dim3(256), 0,
                               stream, x, Wm, attS, attD, h16, aSD, NNODES);
        } else {
            hipLaunchKernelGGL((gemm_mfma_k<__half>), dim3((NNODES + 255) / 256), dim3(256), 0,
                               stream, xh, Wm, attS, attD, h16, aSD, NNODES);
        }
        if (l == 2) {
            hipLaunchKernelGGL((agg_k<false>), dim3((NNODES + 15) / 16), dim3(256), 0, stream,
                               h16, offsL, degL, srcsL, aSD, biasv, d_out);
        } else {
            hipLaunchKernelGGL((agg_k<true>), dim3((NNODES + 15) / 16), dim3(256), 0, stream,
                               h16, offsL, degL, srcsL, aSD, biasv, (void*)xh);
        }
    }
}